// Round 6
// baseline (16699.860 us; speedup 1.0000x reference)
//
#include <hip/hip_runtime.h>
#include <cmath>

#define BB 128
#define TT 512
#define II 256
#define HH 1024
#define K0 1280            // layer0 K (256 x + 1024 h)
#define K1 2048            // layer1 K (1024 feed + 1024 rec)
#define FRAG (BB * 32)     // elems per k-frag panel [128 batch][32 k]

typedef _Float16 half4v __attribute__((ext_vector_type(4)));
typedef _Float16 half8  __attribute__((ext_vector_type(8)));
typedef float    f32x4  __attribute__((ext_vector_type(4)));

__device__ __forceinline__ float sigmoidf_(float x) { return 1.0f / (1.0f + __expf(-x)); }
__device__ __forceinline__ float tanhf_(float x) {
  float xc = fminf(fmaxf(x, -15.f), 15.f);
  float e = __expf(2.f * xc);
  return (e - 1.f) / (e + 1.f);
}

// K-perm within each 32-block: storage p -> logical o
__device__ __host__ __forceinline__ int invP(int p) {
  return 16 * ((p >> 2) & 1) + 4 * (p >> 3) + (p & 3);
}
__device__ __forceinline__ int permP(int o) {
  return 8 * ((o & 15) >> 2) + 4 * (o >> 4) + (o & 3);
}

// ---- convert x fp32 [B][T][I] -> fp16 frag-major [T][g=I/32][B][32perm] ----
__global__ __launch_bounds__(256) void cvt_x_kernel(const float* __restrict__ x,
                                                    _Float16* __restrict__ x16) {
  const int n = blockIdx.x * blockDim.x + threadIdx.x;
  const int q   = n & 3;
  const int b   = (n >> 2) & (BB - 1);
  const int tg  = n >> 9;
  const int t = tg >> 3;
  const int g = tg & 7;
  const float* src = x + ((size_t)b * TT + t) * II + 32 * g;
  const float4 lo = *(const float4*)(src + 4 * q);
  const float4 hi = *(const float4*)(src + 16 + 4 * q);
  half8 o = { (_Float16)lo.x, (_Float16)lo.y, (_Float16)lo.z, (_Float16)lo.w,
              (_Float16)hi.x, (_Float16)hi.y, (_Float16)hi.z, (_Float16)hi.w };
  *(half8*)(x16 + ((size_t)tg * BB + b) * 32 + 8 * q) = o;
}

// ---- gate-interleaved + K-permuted fp16 weight [4096][Ktot]; row' = 4*j + gate ----
__global__ __launch_bounds__(256) void prep_w_kernel(const float* __restrict__ Wih,
    const float* __restrict__ Whh, const float* __restrict__ bih, const float* __restrict__ bhh,
    _Float16* __restrict__ Wr, float* __restrict__ biasr, int Kin) {
  const int Ktot = Kin + HH;
  const int row  = blockIdx.y;
  const int k    = blockIdx.x * blockDim.x + threadIdx.x;
  const int jj = row >> 2, gate = row & 3;
  const int orow = gate * HH + jj;
  if (k < Ktot) {
    const int klog = 32 * (k >> 5) + invP(k & 31);
    float v = (klog < Kin) ? Wih[(size_t)orow * Kin + klog] : Whh[(size_t)orow * HH + (klog - Kin)];
    Wr[(size_t)row * Ktot + k] = (_Float16)v;
  }
  if (blockIdx.x == 0 && threadIdx.x == 0) biasr[row] = bih[orow] + bhh[orow];
}

// ---- K-permuted copy of Wfc ----
__global__ __launch_bounds__(256) void prep_wfc_kernel(const float* __restrict__ Wfc,
                                                       float* __restrict__ wfcp) {
  const int n = blockIdx.x * blockDim.x + threadIdx.x;
  const int k = n & (HH - 1);
  const int o = n >> 10;
  wfcp[n] = Wfc[(size_t)o * HH + 32 * (k >> 5) + invP(k & 31)];
}

#define SB __builtin_amdgcn_sched_barrier(0)

// load one k-frag group: 4 batch-frags of this group's 64-batch slab
#define LOADG(U, BASE) { \
  const _Float16* p_ = (BASE) + boff; \
  U[0] = *(const half8*)(p_); \
  U[1] = *(const half8*)(p_ + 512); \
  U[2] = *(const half8*)(p_ + 1024); \
  U[3] = *(const half8*)(p_ + 1536); }

// 8 MFMAs: 2 row-tiles x 4 batch-frags, k-frag index kf (literal)
#define MFMA8(ACC, U, Aarr, kf) { \
  _Pragma("unroll") for (int f_ = 0; f_ < 4; ++f_) { \
    ACC[0][f_] = __builtin_amdgcn_mfma_f32_16x16x32_f16(Aarr[0][kf], U[f_], ACC[0][f_], 0, 0, 0); \
    ACC[1][f_] = __builtin_amdgcn_mfma_f32_16x16x32_f16(Aarr[1][kf], U[f_], ACC[1][f_], 0, 0, 0); } }

#define L0SRC(f) ((5 * wid + (f)) < 8 ? xt + (5 * wid + (f)) * FRAG \
                                      : h0prev + ((5 * wid + (f)) - 8) * FRAG)
#define L1SRC(f) ((wid < 4) ? h0prev + (8 * wid + (f)) * FRAG \
                            : h1prev + (8 * (wid - 4) + (f)) * FRAG)

// ---- persistent LSTM: G=2 batch split, weights in registers, full-prefetch pipeline,
//      two-level grid barrier ----
__global__ __launch_bounds__(512, 1) void lstm_persist(
    const _Float16* __restrict__ w0r, const _Float16* __restrict__ w1r,
    const float* __restrict__ bias0, const float* __restrict__ bias1,
    const _Float16* __restrict__ x16,
    _Float16* __restrict__ h0buf, _Float16* __restrict__ h1buf,
    unsigned int* cnt)
{
  __shared__ float red[8 * 2048];   // 64KB
  const int tid  = threadIdx.x;
  const int lane = tid & 63;
  const int wid  = tid >> 6;
  const int l15  = lane & 15;
  const int kl   = lane >> 4;
  const int bid  = blockIdx.x;
  const int grp  = bid >> 7;
  const int lbid = bid & 127;

  // ---- A tiles -> registers: 2 row-tiles, K-slice per wave ----
  half8 A0[2][5], A1[2][8];
  #pragma unroll
  for (int t = 0; t < 2; ++t) {
    const _Float16* base0 = w0r + (size_t)(32 * lbid + 16 * t + l15) * K0 + 8 * kl;
    #pragma unroll
    for (int f = 0; f < 5; ++f) A0[t][f] = *(const half8*)(base0 + 32 * (5 * wid + f));
    const _Float16* base1 = w1r + (size_t)(32 * lbid + 16 * t + l15) * K1 + 8 * kl;
    #pragma unroll
    for (int f = 0; f < 8; ++f) A1[t][f] = *(const half8*)(base1 + 32 * (8 * wid + f));
  }
  const int t_own = wid >> 2, f_own = wid & 3;
  const f32x4 bs0 = *(const f32x4*)(bias0 + 32 * lbid + 16 * t_own + 4 * kl);
  const f32x4 bs1 = *(const f32x4*)(bias1 + 32 * lbid + 16 * t_own + 4 * kl);

  const int jj = 8 * lbid + 4 * t_own + kl;          // hidden unit this lane owns
  const int bb = 64 * grp + 16 * f_own + l15;        // batch element this lane owns
  const size_t hwIdx = ((size_t)(jj >> 5) * BB + bb) * 32 + permP(jj & 31);
  const int boff = grp * 2048 + l15 * 32 + 8 * kl;   // within-frag load offset

  // two-level barrier pointers: 16-block sub-counter + per-group root, 256B apart
  unsigned int* subc  = cnt + (grp * 8 + (lbid >> 4)) * 64;
  unsigned int* rootc = cnt + (16 + grp) * 64;
  float c0 = 0.f, c1 = 0.f;
  bool dead = false;

  #pragma unroll 1
  for (int tau = 0; tau <= TT; ++tau) {
    const _Float16* h0prev = h0buf + ((tau + 1) & 1) * (BB * HH);
    _Float16*       h0w    = h0buf + ((tau    ) & 1) * (BB * HH);
    const _Float16* h1prev = h1buf + ((tau    ) & 1) * (BB * HH);
    _Float16*       h1w    = h1buf + ((tau + 1) & 1) * (BB * HH);
    const _Float16* xt     = x16 + (size_t)tau * (BB * II);

    // ---- issue ALL loads for this step up front (13 groups, 52x16B in flight) ----
    half8 P0[4], P1[4], P2[4], P3[4], P4[4];
    half8 Q0[4], Q1[4], Q2[4], Q3[4], Q4[4], Q5[4], Q6[4], Q7[4];
    if (tau < TT) {
      LOADG(P0, L0SRC(0)); LOADG(P1, L0SRC(1)); LOADG(P2, L0SRC(2));
      LOADG(P3, L0SRC(3)); LOADG(P4, L0SRC(4));
    }
    if (tau >= 1) {
      LOADG(Q0, L1SRC(0)); LOADG(Q1, L1SRC(1)); LOADG(Q2, L1SRC(2));
      LOADG(Q3, L1SRC(3)); LOADG(Q4, L1SRC(4)); LOADG(Q5, L1SRC(5));
      LOADG(Q6, L1SRC(6)); LOADG(Q7, L1SRC(7));
    }
    SB;   // pin: no MFMA/LDS op may hoist above; loads may not sink below

    // ---- layer 0: MFMA + reduce + cell update ----
    if (tau < TT) {
      f32x4 acc0[2][4];
      #pragma unroll
      for (int t = 0; t < 2; ++t)
        #pragma unroll
        for (int f = 0; f < 4; ++f) acc0[t][f] = (f32x4){0.f, 0.f, 0.f, 0.f};
      MFMA8(acc0, P0, A0, 0);
      MFMA8(acc0, P1, A0, 1);
      MFMA8(acc0, P2, A0, 2);
      MFMA8(acc0, P3, A0, 3);
      MFMA8(acc0, P4, A0, 4);
      #pragma unroll
      for (int t = 0; t < 2; ++t)
        #pragma unroll
        for (int f = 0; f < 4; ++f)
          *(f32x4*)&red[wid * 2048 + (t * 4 + f) * 256 + lane * 4] = acc0[t][f];
      __syncthreads();
      f32x4 r = {0.f, 0.f, 0.f, 0.f};
      #pragma unroll
      for (int s = 0; s < 8; ++s)
        r += *(const f32x4*)&red[s * 2048 + wid * 256 + lane * 4];
      r += bs0;
      const float gi = sigmoidf_(r[0]);
      const float gf = sigmoidf_(r[1]);
      const float gg = tanhf_(r[2]);
      const float go = sigmoidf_(r[3]);
      c0 = gf * c0 + gi * gg;
      h0w[hwIdx] = (_Float16)(go * tanhf_(c0));
    }
    if (tau >= 1 && tau < TT) __syncthreads();
    // ---- layer 1: MFMA + reduce + cell update ----
    if (tau >= 1) {
      f32x4 acc1[2][4];
      #pragma unroll
      for (int t = 0; t < 2; ++t)
        #pragma unroll
        for (int f = 0; f < 4; ++f) acc1[t][f] = (f32x4){0.f, 0.f, 0.f, 0.f};
      MFMA8(acc1, Q0, A1, 0);
      MFMA8(acc1, Q1, A1, 1);
      MFMA8(acc1, Q2, A1, 2);
      MFMA8(acc1, Q3, A1, 3);
      MFMA8(acc1, Q4, A1, 4);
      MFMA8(acc1, Q5, A1, 5);
      MFMA8(acc1, Q6, A1, 6);
      MFMA8(acc1, Q7, A1, 7);
      #pragma unroll
      for (int t = 0; t < 2; ++t)
        #pragma unroll
        for (int f = 0; f < 4; ++f)
          *(f32x4*)&red[wid * 2048 + (t * 4 + f) * 256 + lane * 4] = acc1[t][f];
      __syncthreads();
      f32x4 r = {0.f, 0.f, 0.f, 0.f};
      #pragma unroll
      for (int s = 0; s < 8; ++s)
        r += *(const f32x4*)&red[s * 2048 + wid * 256 + lane * 4];
      r += bs1;
      const float gi = sigmoidf_(r[0]);
      const float gf = sigmoidf_(r[1]);
      const float gg = tanhf_(r[2]);
      const float go = sigmoidf_(r[3]);
      c1 = gf * c1 + gi * gg;
      h1w[hwIdx] = (_Float16)(go * tanhf_(c1));
    }

    // ---- two-level grid barrier (per batch group) ----
    if (tau < TT) {
      __syncthreads();
      if (tid == 0) {
        __builtin_amdgcn_fence(__ATOMIC_RELEASE, "agent");
        unsigned int old = __hip_atomic_fetch_add(subc, 1u, __ATOMIC_RELAXED,
                                                  __HIP_MEMORY_SCOPE_AGENT);
        if ((old & 15u) == 15u)
          __hip_atomic_fetch_add(rootc, 1u, __ATOMIC_RELAXED, __HIP_MEMORY_SCOPE_AGENT);
        const unsigned int target = 8u * (unsigned int)(tau + 1);
        if (!dead) {
          int guard = 0;
          while (__hip_atomic_load(rootc, __ATOMIC_RELAXED, __HIP_MEMORY_SCOPE_AGENT) < target) {
            __builtin_amdgcn_s_sleep(4);
            if (++guard > (1 << 15)) { dead = true; break; }
          }
        }
        __builtin_amdgcn_fence(__ATOMIC_ACQUIRE, "agent");
      }
      __syncthreads();
    }
  }
}

// ---- final projection on frag-major perm'd h + perm'd Wfc ----
__global__ __launch_bounds__(128) void fc_kernel(const _Float16* __restrict__ h,
    const float* __restrict__ wfcp, const float* __restrict__ bfc, float* __restrict__ out) {
  const int b = blockIdx.x;
  const int o = threadIdx.x;
  const float* wr = wfcp + (size_t)o * HH;
  float s = 0.f;
  #pragma unroll 2
  for (int g = 0; g < 32; ++g) {
    const _Float16* hr = h + ((size_t)g * BB + b) * 32;
    const float* w = wr + g * 32;
    #pragma unroll
    for (int k = 0; k < 32; k += 4) {
      float4 wv = *(const float4*)(w + k);
      half4v hv = *(const half4v*)(hr + k);
      s += (float)hv[0]*wv.x + (float)hv[1]*wv.y + (float)hv[2]*wv.z + (float)hv[3]*wv.w;
    }
  }
  out[(size_t)b * 128 + o] = s + bfc[o];
}

extern "C" void kernel_launch(void* const* d_in, const int* in_sizes, int n_in,
                              void* d_out, int out_size, void* d_ws, size_t ws_size,
                              hipStream_t stream) {
  const float* x    = (const float*)d_in[0];
  const float* Wih0 = (const float*)d_in[1];
  const float* Whh0 = (const float*)d_in[2];
  const float* bih0 = (const float*)d_in[3];
  const float* bhh0 = (const float*)d_in[4];
  const float* Wih1 = (const float*)d_in[5];
  const float* Whh1 = (const float*)d_in[6];
  const float* bih1 = (const float*)d_in[7];
  const float* bhh1 = (const float*)d_in[8];
  const float* Wfc  = (const float*)d_in[9];
  const float* bfc  = (const float*)d_in[10];
  float* out = (float*)d_out;

  char* ws = (char*)d_ws;
  size_t off = 0;
  auto alloc = [&](size_t bytes) -> void* {
    void* p = ws + off;
    off += (bytes + 255) & ~(size_t)255;
    return p;
  };
  _Float16* x16 = (_Float16*)alloc((size_t)BB * TT * II * 2);
  _Float16* w0r = (_Float16*)alloc((size_t)4096 * K0 * 2);
  _Float16* w1r = (_Float16*)alloc((size_t)4096 * K1 * 2);
  float* bias0  = (float*)alloc(4096 * 4);
  float* bias1  = (float*)alloc(4096 * 4);
  float* wfcp   = (float*)alloc((size_t)128 * HH * 4);
  const size_t cntBytes = 64 * 64 * 4;                 // 34 used lines, 256B stride
  const size_t stateBytes = cntBytes + (size_t)2 * BB * HH * 2 * 2;
  char* states  = (char*)alloc(stateBytes);
  unsigned int* cnt = (unsigned int*)states;
  _Float16* h0buf = (_Float16*)(states + cntBytes);
  _Float16* h1buf = h0buf + 2 * BB * HH;

  hipMemsetAsync(states, 0, stateBytes, stream);

  cvt_x_kernel<<<dim3(BB * TT * II / 8 / 256), 256, 0, stream>>>(x, x16);
  prep_w_kernel<<<dim3(K0 / 256, 4096), 256, 0, stream>>>(Wih0, Whh0, bih0, bhh0, w0r, bias0, II);
  prep_w_kernel<<<dim3(K1 / 256, 4096), 256, 0, stream>>>(Wih1, Whh1, bih1, bhh1, w1r, bias1, HH);
  prep_wfc_kernel<<<dim3(128 * HH / 256), 256, 0, stream>>>(Wfc, wfcp);

  void* args[] = { (void*)&w0r, (void*)&w1r, (void*)&bias0, (void*)&bias1,
                   (void*)&x16, (void*)&h0buf, (void*)&h1buf, (void*)&cnt };
  hipLaunchCooperativeKernel((void*)lstm_persist, dim3(256), dim3(512), args, 0, stream);

  fc_kernel<<<dim3(BB), 128, 0, stream>>>(h1buf + (size_t)BB * HH, wfcp, bfc, out);
}

// Round 7
// 10814.066 us; speedup vs baseline: 1.5443x; 1.5443x over previous
//
#include <hip/hip_runtime.h>
#include <cmath>

#define BB 128
#define TT 512
#define II 256
#define HH 1024
#define K0 1280            // layer0 K (256 x + 1024 h)
#define K1 2048            // layer1 K (1024 feed + 1024 rec)
#define FRAG (BB * 32)     // elems per k-frag panel [128 batch][32 k]

typedef _Float16 half4v __attribute__((ext_vector_type(4)));
typedef _Float16 half8  __attribute__((ext_vector_type(8)));
typedef float    f32x4  __attribute__((ext_vector_type(4)));

__device__ __forceinline__ float sigmoidf_(float x) { return 1.0f / (1.0f + __expf(-x)); }
__device__ __forceinline__ float tanhf_(float x) {
  float xc = fminf(fmaxf(x, -15.f), 15.f);
  float e = __expf(2.f * xc);
  return (e - 1.f) / (e + 1.f);
}

// K-perm within each 32-block: storage p -> logical o
__device__ __host__ __forceinline__ int invP(int p) {
  return 16 * ((p >> 2) & 1) + 4 * (p >> 3) + (p & 3);
}
__device__ __forceinline__ int permP(int o) {
  return 8 * ((o & 15) >> 2) + 4 * (o >> 4) + (o & 3);
}

// ---- convert x fp32 [B][T][I] -> fp16 frag-major [T][g=I/32][B][32perm] ----
__global__ __launch_bounds__(256) void cvt_x_kernel(const float* __restrict__ x,
                                                    _Float16* __restrict__ x16) {
  const int n = blockIdx.x * blockDim.x + threadIdx.x;
  const int q   = n & 3;
  const int b   = (n >> 2) & (BB - 1);
  const int tg  = n >> 9;
  const int t = tg >> 3;
  const int g = tg & 7;
  const float* src = x + ((size_t)b * TT + t) * II + 32 * g;
  const float4 lo = *(const float4*)(src + 4 * q);
  const float4 hi = *(const float4*)(src + 16 + 4 * q);
  half8 o = { (_Float16)lo.x, (_Float16)lo.y, (_Float16)lo.z, (_Float16)lo.w,
              (_Float16)hi.x, (_Float16)hi.y, (_Float16)hi.z, (_Float16)hi.w };
  *(half8*)(x16 + ((size_t)tg * BB + b) * 32 + 8 * q) = o;
}

// ---- gate-interleaved + K-permuted fp16 weight [4096][Ktot]; row' = 4*j + gate ----
__global__ __launch_bounds__(256) void prep_w_kernel(const float* __restrict__ Wih,
    const float* __restrict__ Whh, const float* __restrict__ bih, const float* __restrict__ bhh,
    _Float16* __restrict__ Wr, float* __restrict__ biasr, int Kin) {
  const int Ktot = Kin + HH;
  const int row  = blockIdx.y;
  const int k    = blockIdx.x * blockDim.x + threadIdx.x;
  const int jj = row >> 2, gate = row & 3;
  const int orow = gate * HH + jj;
  if (k < Ktot) {
    const int klog = 32 * (k >> 5) + invP(k & 31);
    float v = (klog < Kin) ? Wih[(size_t)orow * Kin + klog] : Whh[(size_t)orow * HH + (klog - Kin)];
    Wr[(size_t)row * Ktot + k] = (_Float16)v;
  }
  if (blockIdx.x == 0 && threadIdx.x == 0) biasr[row] = bih[orow] + bhh[orow];
}

// ---- K-permuted copy of Wfc ----
__global__ __launch_bounds__(256) void prep_wfc_kernel(const float* __restrict__ Wfc,
                                                       float* __restrict__ wfcp) {
  const int n = blockIdx.x * blockDim.x + threadIdx.x;
  const int k = n & (HH - 1);
  const int o = n >> 10;
  wfcp[n] = Wfc[(size_t)o * HH + 32 * (k >> 5) + invP(k & 31)];
}

#define SB __builtin_amdgcn_sched_barrier(0)
#define WAITV { asm volatile("s_waitcnt vmcnt(0)" ::: "memory"); SB; }

// sc0 = L1-bypass, L2-served. Untracked by compiler -> stays in flight across barriers.
#define ALOADG(U, BASE) { \
  const _Float16* p_ = (const _Float16*)(BASE) + boff; \
  asm volatile("global_load_dwordx4 %0, %1, off sc0"             : "=v"(U[0]) : "v"(p_)); \
  asm volatile("global_load_dwordx4 %0, %1, off offset:1024 sc0" : "=v"(U[1]) : "v"(p_)); \
  asm volatile("global_load_dwordx4 %0, %1, off offset:2048 sc0" : "=v"(U[2]) : "v"(p_)); \
  asm volatile("global_load_dwordx4 %0, %1, off offset:3072 sc0" : "=v"(U[3]) : "v"(p_)); }

// 8 MFMAs: 2 row-tiles x 4 batch-frags, k-frag index kf (literal)
#define MFMA8(ACC, U, Aarr, kf) { \
  _Pragma("unroll") for (int f_ = 0; f_ < 4; ++f_) { \
    ACC[0][f_] = __builtin_amdgcn_mfma_f32_16x16x32_f16(Aarr[0][kf], U[f_], ACC[0][f_], 0, 0, 0); \
    ACC[1][f_] = __builtin_amdgcn_mfma_f32_16x16x32_f16(Aarr[1][kf], U[f_], ACC[1][f_], 0, 0, 0); } }

#define L0BASE(f) ((5 * wid + (f)) < 8 ? xt + (5 * wid + (f)) * FRAG \
                                       : h0prev + ((5 * wid + (f)) - 8) * FRAG)
#define L1BASE(f) ((wid < 4) ? h0prev + (8 * wid + (f)) * FRAG \
                             : h1prev + (8 * (wid - 4) + (f)) * FRAG)

// ---- persistent LSTM: G=2 batch split, weights in registers, sc0 loads + leader L2-inv ----
__global__ __launch_bounds__(512, 1) void lstm_persist(
    const _Float16* __restrict__ w0r, const _Float16* __restrict__ w1r,
    const float* __restrict__ bias0, const float* __restrict__ bias1,
    const _Float16* __restrict__ x16,
    _Float16* __restrict__ h0buf, _Float16* __restrict__ h1buf,
    unsigned int* cnt)
{
  __shared__ float red[8 * 2048];   // 64KB
  const int tid  = threadIdx.x;
  const int lane = tid & 63;
  const int wid  = tid >> 6;
  const int l15  = lane & 15;
  const int kl   = lane >> 4;
  const int bid  = blockIdx.x;
  const int grp  = bid >> 7;
  const int lbid = bid & 127;

  // ---- A tiles -> registers: 2 row-tiles, K-slice per wave ----
  half8 A0[2][5], A1[2][8];
  #pragma unroll
  for (int t = 0; t < 2; ++t) {
    const _Float16* base0 = w0r + (size_t)(32 * lbid + 16 * t + l15) * K0 + 8 * kl;
    #pragma unroll
    for (int f = 0; f < 5; ++f) A0[t][f] = *(const half8*)(base0 + 32 * (5 * wid + f));
    const _Float16* base1 = w1r + (size_t)(32 * lbid + 16 * t + l15) * K1 + 8 * kl;
    #pragma unroll
    for (int f = 0; f < 8; ++f) A1[t][f] = *(const half8*)(base1 + 32 * (8 * wid + f));
  }
  const int t_own = wid >> 2, f_own = wid & 3;
  const f32x4 bs0 = *(const f32x4*)(bias0 + 32 * lbid + 16 * t_own + 4 * kl);
  const f32x4 bs1 = *(const f32x4*)(bias1 + 32 * lbid + 16 * t_own + 4 * kl);

  const int jj = 8 * lbid + 4 * t_own + kl;          // hidden unit this lane owns
  const int bb = 64 * grp + 16 * f_own + l15;        // batch element this lane owns
  const size_t hwIdx = ((size_t)(jj >> 5) * BB + bb) * 32 + permP(jj & 31);
  const int boff = grp * 2048 + l15 * 32 + 8 * kl;   // within-frag load offset (halfs)

  // barrier lines (256B apart): [0..15] sub, [16] root, [17+x] xcd epoch, [25+x] xcd go
  unsigned int* subc  = cnt + (bid >> 4) * 64;
  unsigned int* rootc = cnt + 16 * 64;
  float c0 = 0.f, c1 = 0.f;

  #pragma unroll 1
  for (int tau = 0; tau <= TT; ++tau) {
    const _Float16* h0prev = h0buf + ((tau + 1) & 1) * (BB * HH);
    _Float16*       h0w    = h0buf + ((tau    ) & 1) * (BB * HH);
    const _Float16* h1prev = h1buf + ((tau    ) & 1) * (BB * HH);
    _Float16*       h1w    = h1buf + ((tau + 1) & 1) * (BB * HH);
    const _Float16* xt     = x16 + (size_t)tau * (BB * II);

    half8 P0[4], P1[4], P2[4], P3[4], P4[4];   // L0 staging (80 regs)
    half8 Q0[4], Q1[4], Q2[4], Q3[4];          // L1 staging, reused a/b (64 regs)

    // ---------------- layer 0 ----------------
    if (tau < TT) {
      ALOADG(P0, L0BASE(0)); ALOADG(P1, L0BASE(1)); ALOADG(P2, L0BASE(2));
      ALOADG(P3, L0BASE(3)); ALOADG(P4, L0BASE(4));
      WAITV;
      f32x4 acc0[2][4];
      #pragma unroll
      for (int t = 0; t < 2; ++t)
        #pragma unroll
        for (int f = 0; f < 4; ++f) acc0[t][f] = (f32x4){0.f, 0.f, 0.f, 0.f};
      MFMA8(acc0, P0, A0, 0);
      MFMA8(acc0, P1, A0, 1);
      MFMA8(acc0, P2, A0, 2);
      MFMA8(acc0, P3, A0, 3);
      MFMA8(acc0, P4, A0, 4);
      SB;
      // issue L1 first-half loads NOW; latency hides under the L0 reduce
      if (tau >= 1) {
        ALOADG(Q0, L1BASE(0)); ALOADG(Q1, L1BASE(1));
        ALOADG(Q2, L1BASE(2)); ALOADG(Q3, L1BASE(3));
      }
      SB;
      #pragma unroll
      for (int t = 0; t < 2; ++t)
        #pragma unroll
        for (int f = 0; f < 4; ++f)
          *(f32x4*)&red[wid * 2048 + (t * 4 + f) * 256 + lane * 4] = acc0[t][f];
      __syncthreads();
      f32x4 r = {0.f, 0.f, 0.f, 0.f};
      #pragma unroll
      for (int s = 0; s < 8; ++s)
        r += *(const f32x4*)&red[s * 2048 + wid * 256 + lane * 4];
      r += bs0;
      const float gi = sigmoidf_(r[0]);
      const float gf = sigmoidf_(r[1]);
      const float gg = tanhf_(r[2]);
      const float go = sigmoidf_(r[3]);
      c0 = gf * c0 + gi * gg;
      h0w[hwIdx] = (_Float16)(go * tanhf_(c0));
    } else {
      // tau == TT: only layer 1 runs; issue its first-half loads
      ALOADG(Q0, L1BASE(0)); ALOADG(Q1, L1BASE(1));
      ALOADG(Q2, L1BASE(2)); ALOADG(Q3, L1BASE(3));
    }

    if (tau >= 1 && tau < TT) __syncthreads();

    // ---------------- layer 1 (step tau-1) ----------------
    if (tau >= 1) {
      WAITV;
      f32x4 acc1[2][4];
      #pragma unroll
      for (int t = 0; t < 2; ++t)
        #pragma unroll
        for (int f = 0; f < 4; ++f) acc1[t][f] = (f32x4){0.f, 0.f, 0.f, 0.f};
      MFMA8(acc1, Q0, A1, 0);
      MFMA8(acc1, Q1, A1, 1);
      MFMA8(acc1, Q2, A1, 2);
      MFMA8(acc1, Q3, A1, 3);
      SB;
      ALOADG(Q0, L1BASE(4)); ALOADG(Q1, L1BASE(5));
      ALOADG(Q2, L1BASE(6)); ALOADG(Q3, L1BASE(7));
      WAITV;
      MFMA8(acc1, Q0, A1, 4);
      MFMA8(acc1, Q1, A1, 5);
      MFMA8(acc1, Q2, A1, 6);
      MFMA8(acc1, Q3, A1, 7);
      SB;
      #pragma unroll
      for (int t = 0; t < 2; ++t)
        #pragma unroll
        for (int f = 0; f < 4; ++f)
          *(f32x4*)&red[wid * 2048 + (t * 4 + f) * 256 + lane * 4] = acc1[t][f];
      __syncthreads();
      f32x4 r = {0.f, 0.f, 0.f, 0.f};
      #pragma unroll
      for (int s = 0; s < 8; ++s)
        r += *(const f32x4*)&red[s * 2048 + wid * 256 + lane * 4];
      r += bs1;
      const float gi = sigmoidf_(r[0]);
      const float gf = sigmoidf_(r[1]);
      const float gg = tanhf_(r[2]);
      const float go = sigmoidf_(r[3]);
      c1 = gf * c1 + gi * gg;
      h1w[hwIdx] = (_Float16)(go * tanhf_(c1));
    }

    // ---- grid barrier + once-per-XCD L2 invalidate ----
    if (tau < TT) {
      __syncthreads();
      if (tid == 0) {
        __builtin_amdgcn_fence(__ATOMIC_RELEASE, "agent");    // wbl2: publish h writes
        unsigned int old = __hip_atomic_fetch_add(subc, 1u, __ATOMIC_RELAXED,
                                                  __HIP_MEMORY_SCOPE_AGENT);
        if ((old & 15u) == 15u)
          __hip_atomic_fetch_add(rootc, 1u, __ATOMIC_RELAXED, __HIP_MEMORY_SCOPE_AGENT);
        const unsigned int target = 16u * (unsigned int)(tau + 1);
        {
          int guard = 0;
          while (__hip_atomic_load(rootc, __ATOMIC_RELAXED, __HIP_MEMORY_SCOPE_AGENT) < target) {
            __builtin_amdgcn_s_sleep(2);
            if (++guard > (1 << 18)) break;    // escape hatch: no hang
          }
        }
        // leader election per XCD: exactly one block invalidates this XCD's L2
        unsigned int xcd;
        asm volatile("s_getreg_b32 %0, hwreg(HW_REG_XCC_ID)" : "=s"(xcd));
        xcd &= 7u;
        unsigned int* ep = cnt + (17 + xcd) * 64;
        unsigned int* go = cnt + (25 + xcd) * 64;
        unsigned int expct = (unsigned int)tau;
        bool leader = __hip_atomic_compare_exchange_strong(ep, &expct, (unsigned int)(tau + 1),
                        __ATOMIC_RELAXED, __ATOMIC_RELAXED, __HIP_MEMORY_SCOPE_AGENT);
        if (leader) {
          __builtin_amdgcn_fence(__ATOMIC_ACQUIRE, "agent");  // buffer_inv: drop stale L2
          asm volatile("s_waitcnt vmcnt(0)" ::: "memory");
          __hip_atomic_store(go, (unsigned int)(tau + 1), __ATOMIC_RELAXED,
                             __HIP_MEMORY_SCOPE_AGENT);
        } else {
          int guard = 0;
          while (__hip_atomic_load(go, __ATOMIC_RELAXED, __HIP_MEMORY_SCOPE_AGENT)
                 < (unsigned int)(tau + 1)) {
            __builtin_amdgcn_s_sleep(1);
            if (++guard > (1 << 18)) break;
          }
        }
      }
      __syncthreads();
    }
  }
}

// ---- final projection on frag-major perm'd h + perm'd Wfc ----
__global__ __launch_bounds__(128) void fc_kernel(const _Float16* __restrict__ h,
    const float* __restrict__ wfcp, const float* __restrict__ bfc, float* __restrict__ out) {
  const int b = blockIdx.x;
  const int o = threadIdx.x;
  const float* wr = wfcp + (size_t)o * HH;
  float s = 0.f;
  #pragma unroll 2
  for (int g = 0; g < 32; ++g) {
    const _Float16* hr = h + ((size_t)g * BB + b) * 32;
    const float* w = wr + g * 32;
    #pragma unroll
    for (int k = 0; k < 32; k += 4) {
      float4 wv = *(const float4*)(w + k);
      half4v hv = *(const half4v*)(hr + k);
      s += (float)hv[0]*wv.x + (float)hv[1]*wv.y + (float)hv[2]*wv.z + (float)hv[3]*wv.w;
    }
  }
  out[(size_t)b * 128 + o] = s + bfc[o];
}

extern "C" void kernel_launch(void* const* d_in, const int* in_sizes, int n_in,
                              void* d_out, int out_size, void* d_ws, size_t ws_size,
                              hipStream_t stream) {
  const float* x    = (const float*)d_in[0];
  const float* Wih0 = (const float*)d_in[1];
  const float* Whh0 = (const float*)d_in[2];
  const float* bih0 = (const float*)d_in[3];
  const float* bhh0 = (const float*)d_in[4];
  const float* Wih1 = (const float*)d_in[5];
  const float* Whh1 = (const float*)d_in[6];
  const float* bih1 = (const float*)d_in[7];
  const float* bhh1 = (const float*)d_in[8];
  const float* Wfc  = (const float*)d_in[9];
  const float* bfc  = (const float*)d_in[10];
  float* out = (float*)d_out;

  char* ws = (char*)d_ws;
  size_t off = 0;
  auto alloc = [&](size_t bytes) -> void* {
    void* p = ws + off;
    off += (bytes + 255) & ~(size_t)255;
    return p;
  };
  _Float16* x16 = (_Float16*)alloc((size_t)BB * TT * II * 2);
  _Float16* w0r = (_Float16*)alloc((size_t)4096 * K0 * 2);
  _Float16* w1r = (_Float16*)alloc((size_t)4096 * K1 * 2);
  float* bias0  = (float*)alloc(4096 * 4);
  float* bias1  = (float*)alloc(4096 * 4);
  float* wfcp   = (float*)alloc((size_t)128 * HH * 4);
  const size_t cntBytes = 64 * 64 * 4;                 // 33 used lines, 256B stride
  const size_t stateBytes = cntBytes + (size_t)2 * BB * HH * 2 * 2;
  char* states  = (char*)alloc(stateBytes);
  unsigned int* cnt = (unsigned int*)states;
  _Float16* h0buf = (_Float16*)(states + cntBytes);
  _Float16* h1buf = h0buf + 2 * BB * HH;

  hipMemsetAsync(states, 0, stateBytes, stream);

  cvt_x_kernel<<<dim3(BB * TT * II / 8 / 256), 256, 0, stream>>>(x, x16);
  prep_w_kernel<<<dim3(K0 / 256, 4096), 256, 0, stream>>>(Wih0, Whh0, bih0, bhh0, w0r, bias0, II);
  prep_w_kernel<<<dim3(K1 / 256, 4096), 256, 0, stream>>>(Wih1, Whh1, bih1, bhh1, w1r, bias1, HH);
  prep_wfc_kernel<<<dim3(128 * HH / 256), 256, 0, stream>>>(Wfc, wfcp);

  void* args[] = { (void*)&w0r, (void*)&w1r, (void*)&bias0, (void*)&bias1,
                   (void*)&x16, (void*)&h0buf, (void*)&h1buf, (void*)&cnt };
  hipLaunchCooperativeKernel((void*)lstm_persist, dim3(256), dim3(512), args, 0, stream);

  fc_kernel<<<dim3(BB), 128, 0, stream>>>(h1buf + (size_t)BB * HH, wfcp, bfc, out);
}

// Round 11
// 8983.499 us; speedup vs baseline: 1.8589x; 1.2038x over previous
//
#include <hip/hip_runtime.h>
#include <cmath>

#define BB 128
#define TT 512
#define II 256
#define HH 1024
#define K0 1280            // layer0 K (256 x + 1024 h)
#define K1 2048            // layer1 K (1024 feed + 1024 rec)
#define FRAG (BB * 32)     // elems per k-frag panel [128 batch][32 k]

typedef _Float16 half4v __attribute__((ext_vector_type(4)));
typedef _Float16 half8  __attribute__((ext_vector_type(8)));
typedef float    f32x4  __attribute__((ext_vector_type(4)));

__device__ __forceinline__ float sigmoidf_(float x) { return 1.0f / (1.0f + __expf(-x)); }
__device__ __forceinline__ float tanhf_(float x) {
  float xc = fminf(fmaxf(x, -15.f), 15.f);
  float e = __expf(2.f * xc);
  return (e - 1.f) / (e + 1.f);
}

// K-perm within each 32-block: storage p -> logical o
__device__ __host__ __forceinline__ int invP(int p) {
  return 16 * ((p >> 2) & 1) + 4 * (p >> 3) + (p & 3);
}
__device__ __forceinline__ int permP(int o) {
  return 8 * ((o & 15) >> 2) + 4 * (o >> 4) + (o & 3);
}

// ---- convert x fp32 [B][T][I] -> fp16 frag-major [T][g=I/32][B][32perm] ----
__global__ __launch_bounds__(256) void cvt_x_kernel(const float* __restrict__ x,
                                                    _Float16* __restrict__ x16) {
  const int n = blockIdx.x * blockDim.x + threadIdx.x;
  const int q   = n & 3;
  const int b   = (n >> 2) & (BB - 1);
  const int tg  = n >> 9;
  const int t = tg >> 3;
  const int g = tg & 7;
  const float* src = x + ((size_t)b * TT + t) * II + 32 * g;
  const float4 lo = *(const float4*)(src + 4 * q);
  const float4 hi = *(const float4*)(src + 16 + 4 * q);
  half8 o = { (_Float16)lo.x, (_Float16)lo.y, (_Float16)lo.z, (_Float16)lo.w,
              (_Float16)hi.x, (_Float16)hi.y, (_Float16)hi.z, (_Float16)hi.w };
  *(half8*)(x16 + ((size_t)tg * BB + b) * 32 + 8 * q) = o;
}

// ---- gate-interleaved + K-permuted fp16 weight [4096][Ktot]; row' = 4*j + gate ----
__global__ __launch_bounds__(256) void prep_w_kernel(const float* __restrict__ Wih,
    const float* __restrict__ Whh, const float* __restrict__ bih, const float* __restrict__ bhh,
    _Float16* __restrict__ Wr, float* __restrict__ biasr, int Kin) {
  const int Ktot = Kin + HH;
  const int row  = blockIdx.y;
  const int k    = blockIdx.x * blockDim.x + threadIdx.x;
  const int jj = row >> 2, gate = row & 3;
  const int orow = gate * HH + jj;
  if (k < Ktot) {
    const int klog = 32 * (k >> 5) + invP(k & 31);
    float v = (klog < Kin) ? Wih[(size_t)orow * Kin + klog] : Whh[(size_t)orow * HH + (klog - Kin)];
    Wr[(size_t)row * Ktot + k] = (_Float16)v;
  }
  if (blockIdx.x == 0 && threadIdx.x == 0) biasr[row] = bih[orow] + bhh[orow];
}

// ---- K-permuted copy of Wfc ----
__global__ __launch_bounds__(256) void prep_wfc_kernel(const float* __restrict__ Wfc,
                                                       float* __restrict__ wfcp) {
  const int n = blockIdx.x * blockDim.x + threadIdx.x;
  const int k = n & (HH - 1);
  const int o = n >> 10;
  wfcp[n] = Wfc[(size_t)o * HH + 32 * (k >> 5) + invP(k & 31)];
}

#define SB __builtin_amdgcn_sched_barrier(0)
#define VW(n) { asm volatile("s_waitcnt vmcnt(" #n ")" ::: "memory"); SB; }

// sc0 = L1-bypass, L2-served. Untracked by compiler -> stays in flight across barriers.
#define ALOADG(U, BASE) { \
  const _Float16* p_ = (const _Float16*)(BASE) + boff; \
  asm volatile("global_load_dwordx4 %0, %1, off sc0"             : "=v"(U[0]) : "v"(p_)); \
  asm volatile("global_load_dwordx4 %0, %1, off offset:1024 sc0" : "=v"(U[1]) : "v"(p_)); \
  asm volatile("global_load_dwordx4 %0, %1, off offset:2048 sc0" : "=v"(U[2]) : "v"(p_)); \
  asm volatile("global_load_dwordx4 %0, %1, off offset:3072 sc0" : "=v"(U[3]) : "v"(p_)); }

// 2B h-store (L2 write-back); issued ONLY after all loads of the step -> vmcnt stream
// during MFMA ladders is loads-only (loads retire in order; stores don't order vs loads)
#define HSTORE(PTR, VAL) { unsigned int d_ = (VAL); \
  asm volatile("global_store_short %0, %1, off sc0" :: "v"(PTR), "v"(d_) : "memory"); }

// 8 MFMAs: 2 row-tiles x 4 batch-frags, k-frag index kf (literal)
#define MFMA8(ACC, U, Aarr, kf) { \
  _Pragma("unroll") for (int f_ = 0; f_ < 4; ++f_) { \
    ACC[0][f_] = __builtin_amdgcn_mfma_f32_16x16x32_f16(Aarr[0][kf], U[f_], ACC[0][f_], 0, 0, 0); \
    ACC[1][f_] = __builtin_amdgcn_mfma_f32_16x16x32_f16(Aarr[1][kf], U[f_], ACC[1][f_], 0, 0, 0); } }

#define L0BASE(f) ((5 * wid + (f)) < 8 ? xt + (5 * wid + (f)) * FRAG \
                                       : h0prev + ((5 * wid + (f)) - 8) * FRAG)
#define L1BASE(f) ((wid < 4) ? h0prev + (8 * wid + (f)) * FRAG \
                             : h1prev + (8 * (wid - 4) + (f)) * FRAG)

// ---- persistent LSTM: G=2 batch split, loads-only counted ladders, deferred h-stores ----
__global__ __launch_bounds__(512, 1) void lstm_persist(
    const _Float16* __restrict__ w0r, const _Float16* __restrict__ w1r,
    const float* __restrict__ bias0, const float* __restrict__ bias1,
    const _Float16* __restrict__ x16,
    _Float16* __restrict__ h0buf, _Float16* __restrict__ h1buf,
    unsigned int* cnt)
{
  __shared__ float red[8 * 2048];   // 64KB
  const int tid  = threadIdx.x;
  const int lane = tid & 63;
  const int wid  = tid >> 6;
  const int l15  = lane & 15;
  const int kl   = lane >> 4;
  const int bid  = blockIdx.x;
  const int grp  = bid >> 7;
  const int lbid = bid & 127;

  // ---- A tiles -> registers: 2 row-tiles, K-slice per wave ----
  half8 A0[2][5], A1[2][8];
  #pragma unroll
  for (int t = 0; t < 2; ++t) {
    const _Float16* base0 = w0r + (size_t)(32 * lbid + 16 * t + l15) * K0 + 8 * kl;
    #pragma unroll
    for (int f = 0; f < 5; ++f) A0[t][f] = *(const half8*)(base0 + 32 * (5 * wid + f));
    const _Float16* base1 = w1r + (size_t)(32 * lbid + 16 * t + l15) * K1 + 8 * kl;
    #pragma unroll
    for (int f = 0; f < 8; ++f) A1[t][f] = *(const half8*)(base1 + 32 * (8 * wid + f));
  }
  const int t_own = wid >> 2, f_own = wid & 3;
  const f32x4 bs0 = *(const f32x4*)(bias0 + 32 * lbid + 16 * t_own + 4 * kl);
  const f32x4 bs1 = *(const f32x4*)(bias1 + 32 * lbid + 16 * t_own + 4 * kl);

  const int jj = 8 * lbid + 4 * t_own + kl;          // hidden unit this lane owns
  const int bb = 64 * grp + 16 * f_own + l15;        // batch element this lane owns
  const size_t hwIdx = ((size_t)(jj >> 5) * BB + bb) * 32 + permP(jj & 31);
  const int boff = grp * 2048 + l15 * 32 + 8 * kl;   // within-frag load offset (halfs)

  // barrier lines (256B stride): [0..15] sub, [16] root, [17+x] xcd epoch, [25+x] xcd go
  unsigned int* subc  = cnt + (bid >> 4) * 64;
  unsigned int* rootc = cnt + 16 * 64;
  unsigned int xcd;
  asm volatile("s_getreg_b32 %0, hwreg(HW_REG_XCC_ID)" : "=s"(xcd));
  xcd &= 7u;
  unsigned int* ep = cnt + (17 + xcd) * 64;
  unsigned int* go = cnt + (25 + xcd) * 64;

  float c0 = 0.f, c1 = 0.f;

  #pragma unroll 1
  for (int tau = 0; tau <= TT; ++tau) {
    const _Float16* h0prev = h0buf + ((tau + 1) & 1) * (BB * HH);
    _Float16*       h0w    = h0buf + ((tau    ) & 1) * (BB * HH);
    const _Float16* h1prev = h1buf + ((tau    ) & 1) * (BB * HH);
    _Float16*       h1w    = h1buf + ((tau + 1) & 1) * (BB * HH);
    const _Float16* xt     = x16 + (size_t)tau * (BB * II);

    half8 P0[4], P1[4], P2[4], P3[4], P4[4];   // L0 staging (80 regs)
    half8 Q0[4], Q1[4], Q2[4], Q3[4];          // L1 staging, reused for both halves
    unsigned short hv0 = 0, hv1 = 0;           // deferred h values

    // ---------------- layer 0 (loads-only counted ladder) ----------------
    if (tau < TT) {
      ALOADG(P0, L0BASE(0)); ALOADG(P1, L0BASE(1)); ALOADG(P2, L0BASE(2));
      ALOADG(P3, L0BASE(3)); ALOADG(P4, L0BASE(4));
      f32x4 acc0[2][4];
      #pragma unroll
      for (int t = 0; t < 2; ++t)
        #pragma unroll
        for (int f = 0; f < 4; ++f) acc0[t][f] = (f32x4){0.f, 0.f, 0.f, 0.f};
      VW(16); MFMA8(acc0, P0, A0, 0);
      VW(12); MFMA8(acc0, P1, A0, 1);
      VW(8);  MFMA8(acc0, P2, A0, 2);
      VW(4);  MFMA8(acc0, P3, A0, 3);
      VW(0);  MFMA8(acc0, P4, A0, 4);
      SB;
      // L1 first-half loads: latency hides under the L0 reduce
      if (tau >= 1) {
        ALOADG(Q0, L1BASE(0)); ALOADG(Q1, L1BASE(1));
        ALOADG(Q2, L1BASE(2)); ALOADG(Q3, L1BASE(3));
      }
      SB;
      #pragma unroll
      for (int t = 0; t < 2; ++t)
        #pragma unroll
        for (int f = 0; f < 4; ++f)
          *(f32x4*)&red[wid * 2048 + (t * 4 + f) * 256 + lane * 4] = acc0[t][f];
      __syncthreads();
      f32x4 r = {0.f, 0.f, 0.f, 0.f};
      #pragma unroll
      for (int s = 0; s < 8; ++s)
        r += *(const f32x4*)&red[s * 2048 + wid * 256 + lane * 4];
      r += bs0;
      const float gi = sigmoidf_(r[0]);
      const float gf = sigmoidf_(r[1]);
      const float gg = tanhf_(r[2]);
      const float go_ = sigmoidf_(r[3]);
      c0 = gf * c0 + gi * gg;
      _Float16 h_ = (_Float16)(go_ * tanhf_(c0));
      hv0 = __builtin_bit_cast(unsigned short, h_);   // store deferred to end of step
    } else {
      // tau == TT: only layer 1; its first-half loads
      ALOADG(Q0, L1BASE(0)); ALOADG(Q1, L1BASE(1));
      ALOADG(Q2, L1BASE(2)); ALOADG(Q3, L1BASE(3));
    }

    if (tau >= 1 && tau < TT) __syncthreads();   // WAR guard on red between layer reduces

    // ---------------- layer 1 (step tau-1): loads-only ladder, Q reuse ----------------
    if (tau >= 1) {
      f32x4 acc1[2][4];
      #pragma unroll
      for (int t = 0; t < 2; ++t)
        #pragma unroll
        for (int f = 0; f < 4; ++f) acc1[t][f] = (f32x4){0.f, 0.f, 0.f, 0.f};
      // outstanding: Q0..Q3 = 16 loads, nothing else in the vmcnt stream
      VW(12); MFMA8(acc1, Q0, A1, 0); ALOADG(Q0, L1BASE(4));
      VW(12); MFMA8(acc1, Q1, A1, 1); ALOADG(Q1, L1BASE(5));
      VW(12); MFMA8(acc1, Q2, A1, 2); ALOADG(Q2, L1BASE(6));
      VW(12); MFMA8(acc1, Q3, A1, 3); ALOADG(Q3, L1BASE(7));
      VW(12); MFMA8(acc1, Q0, A1, 4);
      VW(8);  MFMA8(acc1, Q1, A1, 5);
      VW(4);  MFMA8(acc1, Q2, A1, 6);
      VW(0);  MFMA8(acc1, Q3, A1, 7);
      SB;
      #pragma unroll
      for (int t = 0; t < 2; ++t)
        #pragma unroll
        for (int f = 0; f < 4; ++f)
          *(f32x4*)&red[wid * 2048 + (t * 4 + f) * 256 + lane * 4] = acc1[t][f];
      __syncthreads();
      f32x4 r = {0.f, 0.f, 0.f, 0.f};
      #pragma unroll
      for (int s = 0; s < 8; ++s)
        r += *(const f32x4*)&red[s * 2048 + wid * 256 + lane * 4];
      r += bs1;
      const float gi = sigmoidf_(r[0]);
      const float gf = sigmoidf_(r[1]);
      const float gg = tanhf_(r[2]);
      const float go_ = sigmoidf_(r[3]);
      c1 = gf * c1 + gi * gg;
      _Float16 h_ = (_Float16)(go_ * tanhf_(c1));
      hv1 = __builtin_bit_cast(unsigned short, h_);
    }

    // ---- deferred h-stores: AFTER all loads of this step have been issued ----
    if (tau < TT) HSTORE(h0w + hwIdx, (unsigned int)hv0);
    if (tau >= 1) HSTORE(h1w + hwIdx, (unsigned int)hv1);

    // ---- grid barrier: all-wave store drain -> release fence -> hierarchical spin ----
    if (tau < TT) {
      asm volatile("s_waitcnt vmcnt(0)" ::: "memory");   // EVERY wave drains its h-stores
      __syncthreads();
      if (tid == 0) {
        __builtin_amdgcn_fence(__ATOMIC_RELEASE, "agent");   // wbl2: publish h to L3
        unsigned int old = __hip_atomic_fetch_add(subc, 1u, __ATOMIC_RELAXED,
                                                  __HIP_MEMORY_SCOPE_AGENT);
        if ((old & 15u) == 15u)
          __hip_atomic_fetch_add(rootc, 1u, __ATOMIC_RELAXED, __HIP_MEMORY_SCOPE_AGENT);
        unsigned int expct = (unsigned int)tau;
        const bool leader = __hip_atomic_compare_exchange_strong(ep, &expct,
                              (unsigned int)(tau + 1), __ATOMIC_RELAXED, __ATOMIC_RELAXED,
                              __HIP_MEMORY_SCOPE_AGENT);
        const unsigned int target = 16u * (unsigned int)(tau + 1);
        if (leader) {
          int g_ = 0;
          while (__hip_atomic_load(rootc, __ATOMIC_RELAXED, __HIP_MEMORY_SCOPE_AGENT) < target) {
            __builtin_amdgcn_s_sleep(4);
            if (++g_ > (1 << 17)) break;   // escape hatch: no hang
          }
          __builtin_amdgcn_fence(__ATOMIC_ACQUIRE, "agent");  // one buffer_inv per XCD
          __hip_atomic_store(go, (unsigned int)(tau + 1), __ATOMIC_RELAXED,
                             __HIP_MEMORY_SCOPE_AGENT);
        } else {
          int g_ = 0;
          while (__hip_atomic_load(go, __ATOMIC_RELAXED, __HIP_MEMORY_SCOPE_AGENT)
                 < (unsigned int)(tau + 1)) {
            __builtin_amdgcn_s_sleep(8);
            if (++g_ > (1 << 17)) break;
          }
        }
        asm volatile("s_waitcnt vmcnt(0)" ::: "memory");   // drain go-store / polls
      }
      __syncthreads();
    }
  }

  // final drain: untracked h1 store must complete before kernel end (fc reads it next)
  asm volatile("s_waitcnt vmcnt(0)" ::: "memory");
}

// ---- final projection on frag-major perm'd h + perm'd Wfc ----
__global__ __launch_bounds__(128) void fc_kernel(const _Float16* __restrict__ h,
    const float* __restrict__ wfcp, const float* __restrict__ bfc, float* __restrict__ out) {
  const int b = blockIdx.x;
  const int o = threadIdx.x;
  const float* wr = wfcp + (size_t)o * HH;
  float s = 0.f;
  #pragma unroll 2
  for (int g = 0; g < 32; ++g) {
    const _Float16* hr = h + ((size_t)g * BB + b) * 32;
    const float* w = wr + g * 32;
    #pragma unroll
    for (int k = 0; k < 32; k += 4) {
      float4 wv = *(const float4*)(w + k);
      half4v hv = *(const half4v*)(hr + k);
      s += (float)hv[0]*wv.x + (float)hv[1]*wv.y + (float)hv[2]*wv.z + (float)hv[3]*wv.w;
    }
  }
  out[(size_t)b * 128 + o] = s + bfc[o];
}

extern "C" void kernel_launch(void* const* d_in, const int* in_sizes, int n_in,
                              void* d_out, int out_size, void* d_ws, size_t ws_size,
                              hipStream_t stream) {
  const float* x    = (const float*)d_in[0];
  const float* Wih0 = (const float*)d_in[1];
  const float* Whh0 = (const float*)d_in[2];
  const float* bih0 = (const float*)d_in[3];
  const float* bhh0 = (const float*)d_in[4];
  const float* Wih1 = (const float*)d_in[5];
  const float* Whh1 = (const float*)d_in[6];
  const float* bih1 = (const float*)d_in[7];
  const float* bhh1 = (const float*)d_in[8];
  const float* Wfc  = (const float*)d_in[9];
  const float* bfc  = (const float*)d_in[10];
  float* out = (float*)d_out;

  char* ws = (char*)d_ws;
  size_t off = 0;
  auto alloc = [&](size_t bytes) -> void* {
    void* p = ws + off;
    off += (bytes + 255) & ~(size_t)255;
    return p;
  };
  _Float16* x16 = (_Float16*)alloc((size_t)BB * TT * II * 2);
  _Float16* w0r = (_Float16*)alloc((size_t)4096 * K0 * 2);
  _Float16* w1r = (_Float16*)alloc((size_t)4096 * K1 * 2);
  float* bias0  = (float*)alloc(4096 * 4);
  float* bias1  = (float*)alloc(4096 * 4);
  float* wfcp   = (float*)alloc((size_t)128 * HH * 4);
  const size_t cntBytes = 64 * 64 * 4;                 // lines 0..32 used, 256B stride
  const size_t stateBytes = cntBytes + (size_t)2 * BB * HH * 2 * 2;
  char* states  = (char*)alloc(stateBytes);
  unsigned int* cnt = (unsigned int*)states;
  _Float16* h0buf = (_Float16*)(states + cntBytes);
  _Float16* h1buf = h0buf + 2 * BB * HH;

  hipMemsetAsync(states, 0, stateBytes, stream);

  cvt_x_kernel<<<dim3(BB * TT * II / 8 / 256), 256, 0, stream>>>(x, x16);
  prep_w_kernel<<<dim3(K0 / 256, 4096), 256, 0, stream>>>(Wih0, Whh0, bih0, bhh0, w0r, bias0, II);
  prep_w_kernel<<<dim3(K1 / 256, 4096), 256, 0, stream>>>(Wih1, Whh1, bih1, bhh1, w1r, bias1, HH);
  prep_wfc_kernel<<<dim3(128 * HH / 256), 256, 0, stream>>>(Wfc, wfcp);

  void* args[] = { (void*)&w0r, (void*)&w1r, (void*)&bias0, (void*)&bias1,
                   (void*)&x16, (void*)&h0buf, (void*)&h1buf, (void*)&cnt };
  hipLaunchCooperativeKernel((void*)lstm_persist, dim3(256), dim3(512), args, 0, stream);

  fc_kernel<<<dim3(BB), 128, 0, stream>>>(h1buf + (size_t)BB * HH, wfcp, bfc, out);
}

// Round 12
// 6402.572 us; speedup vs baseline: 2.6083x; 1.4031x over previous
//
#include <hip/hip_runtime.h>
#include <cmath>

#define BB 128
#define TT 512
#define II 256
#define HH 1024
#define K0 1280            // layer0 K (256 x + 1024 h)
#define K1 2048            // layer1 K (1024 feed + 1024 rec)
#define FRAG (BB * 32)     // elems per k-frag panel [128 batch][32 k]

typedef _Float16 half4v __attribute__((ext_vector_type(4)));
typedef _Float16 half8  __attribute__((ext_vector_type(8)));
typedef float    f32x4  __attribute__((ext_vector_type(4)));

__device__ __forceinline__ float sigmoidf_(float x) { return 1.0f / (1.0f + __expf(-x)); }
__device__ __forceinline__ float tanhf_(float x) {
  float xc = fminf(fmaxf(x, -15.f), 15.f);
  float e = __expf(2.f * xc);
  return (e - 1.f) / (e + 1.f);
}

// K-perm within each 32-block: storage p -> logical o
__device__ __host__ __forceinline__ int invP(int p) {
  return 16 * ((p >> 2) & 1) + 4 * (p >> 3) + (p & 3);
}
__device__ __forceinline__ int permP(int o) {
  return 8 * ((o & 15) >> 2) + 4 * (o >> 4) + (o & 3);
}

// ---- convert x fp32 [B][T][I] -> fp16 frag-major [T][g=I/32][B][32perm] ----
__global__ __launch_bounds__(256) void cvt_x_kernel(const float* __restrict__ x,
                                                    _Float16* __restrict__ x16) {
  const int n = blockIdx.x * blockDim.x + threadIdx.x;
  const int q   = n & 3;
  const int b   = (n >> 2) & (BB - 1);
  const int tg  = n >> 9;
  const int t = tg >> 3;
  const int g = tg & 7;
  const float* src = x + ((size_t)b * TT + t) * II + 32 * g;
  const float4 lo = *(const float4*)(src + 4 * q);
  const float4 hi = *(const float4*)(src + 16 + 4 * q);
  half8 o = { (_Float16)lo.x, (_Float16)lo.y, (_Float16)lo.z, (_Float16)lo.w,
              (_Float16)hi.x, (_Float16)hi.y, (_Float16)hi.z, (_Float16)hi.w };
  *(half8*)(x16 + ((size_t)tg * BB + b) * 32 + 8 * q) = o;
}

// ---- gate-interleaved + K-permuted fp16 weight [4096][Ktot]; row' = 4*j + gate ----
__global__ __launch_bounds__(256) void prep_w_kernel(const float* __restrict__ Wih,
    const float* __restrict__ Whh, const float* __restrict__ bih, const float* __restrict__ bhh,
    _Float16* __restrict__ Wr, float* __restrict__ biasr, int Kin) {
  const int Ktot = Kin + HH;
  const int row  = blockIdx.y;
  const int k    = blockIdx.x * blockDim.x + threadIdx.x;
  const int jj = row >> 2, gate = row & 3;
  const int orow = gate * HH + jj;
  if (k < Ktot) {
    const int klog = 32 * (k >> 5) + invP(k & 31);
    float v = (klog < Kin) ? Wih[(size_t)orow * Kin + klog] : Whh[(size_t)orow * HH + (klog - Kin)];
    Wr[(size_t)row * Ktot + k] = (_Float16)v;
  }
  if (blockIdx.x == 0 && threadIdx.x == 0) biasr[row] = bih[orow] + bhh[orow];
}

// ---- K-permuted copy of Wfc ----
__global__ __launch_bounds__(256) void prep_wfc_kernel(const float* __restrict__ Wfc,
                                                       float* __restrict__ wfcp) {
  const int n = blockIdx.x * blockDim.x + threadIdx.x;
  const int k = n & (HH - 1);
  const int o = n >> 10;
  wfcp[n] = Wfc[(size_t)o * HH + 32 * (k >> 5) + invP(k & 31)];
}

#define SB __builtin_amdgcn_sched_barrier(0)
#define VW(n) { asm volatile("s_waitcnt vmcnt(" #n ")" ::: "memory"); SB; }

// sc0 = L1-bypass, L2-served. Untracked by compiler -> stays in flight across barriers.
#define ALOADG(U, BASE) { \
  const _Float16* p_ = (const _Float16*)(BASE) + boff; \
  asm volatile("global_load_dwordx4 %0, %1, off sc0"             : "=v"(U[0]) : "v"(p_)); \
  asm volatile("global_load_dwordx4 %0, %1, off offset:1024 sc0" : "=v"(U[1]) : "v"(p_)); \
  asm volatile("global_load_dwordx4 %0, %1, off offset:2048 sc0" : "=v"(U[2]) : "v"(p_)); \
  asm volatile("global_load_dwordx4 %0, %1, off offset:3072 sc0" : "=v"(U[3]) : "v"(p_)); }

// 2B h-store (L2 write-back); issued ONLY after all loads of the step -> vmcnt stream
// during MFMA ladders is loads-only (loads retire in order; stores don't order vs loads)
#define HSTORE(PTR, VAL) { unsigned int d_ = (VAL); \
  asm volatile("global_store_short %0, %1, off sc0" :: "v"(PTR), "v"(d_) : "memory"); }

// 8 MFMAs: 2 row-tiles x 4 batch-frags, k-frag index kf (literal)
#define MFMA8(ACC, U, Aarr, kf) { \
  _Pragma("unroll") for (int f_ = 0; f_ < 4; ++f_) { \
    ACC[0][f_] = __builtin_amdgcn_mfma_f32_16x16x32_f16(Aarr[0][kf], U[f_], ACC[0][f_], 0, 0, 0); \
    ACC[1][f_] = __builtin_amdgcn_mfma_f32_16x16x32_f16(Aarr[1][kf], U[f_], ACC[1][f_], 0, 0, 0); } }

#define L0BASE(f) ((5 * wid + (f)) < 8 ? xt + (5 * wid + (f)) * FRAG \
                                       : h0prev + ((5 * wid + (f)) - 8) * FRAG)
#define L1BASE(f) ((wid < 4) ? h0prev + (8 * wid + (f)) * FRAG \
                             : h1prev + (8 * (wid - 4) + (f)) * FRAG)

// ---- persistent LSTM: loads-only ladders, deferred h-stores, per-XCD-leader barrier ----
// Barrier v3: one wbl2 + one inv per XCD per step (leaders only), vs 256 wbl2 before.
__global__ __launch_bounds__(512, 1) void lstm_persist(
    const _Float16* __restrict__ w0r, const _Float16* __restrict__ w1r,
    const float* __restrict__ bias0, const float* __restrict__ bias1,
    const _Float16* __restrict__ x16,
    _Float16* __restrict__ h0buf, _Float16* __restrict__ h1buf,
    unsigned int* cnt)
{
  __shared__ float red[8 * 2048];   // 64KB
  const int tid  = threadIdx.x;
  const int lane = tid & 63;
  const int wid  = tid >> 6;
  const int l15  = lane & 15;
  const int kl   = lane >> 4;
  const int bid  = blockIdx.x;
  const int grp  = bid >> 7;
  const int lbid = bid & 127;

  // ---- A tiles -> registers: 2 row-tiles, K-slice per wave ----
  half8 A0[2][5], A1[2][8];
  #pragma unroll
  for (int t = 0; t < 2; ++t) {
    const _Float16* base0 = w0r + (size_t)(32 * lbid + 16 * t + l15) * K0 + 8 * kl;
    #pragma unroll
    for (int f = 0; f < 5; ++f) A0[t][f] = *(const half8*)(base0 + 32 * (5 * wid + f));
    const _Float16* base1 = w1r + (size_t)(32 * lbid + 16 * t + l15) * K1 + 8 * kl;
    #pragma unroll
    for (int f = 0; f < 8; ++f) A1[t][f] = *(const half8*)(base1 + 32 * (8 * wid + f));
  }
  const int t_own = wid >> 2, f_own = wid & 3;
  const f32x4 bs0 = *(const f32x4*)(bias0 + 32 * lbid + 16 * t_own + 4 * kl);
  const f32x4 bs1 = *(const f32x4*)(bias1 + 32 * lbid + 16 * t_own + 4 * kl);

  const int jj = 8 * lbid + 4 * t_own + kl;          // hidden unit this lane owns
  const int bb = 64 * grp + 16 * f_own + l15;        // batch element this lane owns
  const size_t hwIdx = ((size_t)(jj >> 5) * BB + bb) * 32 + permP(jj & 31);
  const int boff = grp * 2048 + l15 * 32 + 8 * kl;   // within-frag load offset (halfs)

  // cnt lines (256B stride): [0..7] xcd arrivals, [8..15] xcd go, [16] root,
  //                          [17..24] election, [25..32] xcd block count, [33] pre-barrier
  unsigned int xcd;
  asm volatile("s_getreg_b32 %0, hwreg(HW_REG_XCC_ID)" : "=s"(xcd));
  xcd &= 7u;
  unsigned int* xarr   = cnt + (0  + xcd) * 64;
  unsigned int* go     = cnt + (8  + xcd) * 64;
  unsigned int* rootc  = cnt + 16 * 64;
  unsigned int* ep     = cnt + (17 + xcd) * 64;
  unsigned int* xcnt   = cnt + (25 + xcd) * 64;
  unsigned int* preb   = cnt + 33 * 64;

  // ---- pre-loop: count blocks per XCD, flat pre-barrier, elect persistent leader ----
  bool isLeader = false;
  unsigned int nblkx = 0;
  if (tid == 0) {
    __hip_atomic_fetch_add(xcnt, 1u, __ATOMIC_RELAXED, __HIP_MEMORY_SCOPE_AGENT);
    asm volatile("s_waitcnt vmcnt(0)" ::: "memory");   // order xcnt add before preb add
    __hip_atomic_fetch_add(preb, 1u, __ATOMIC_RELAXED, __HIP_MEMORY_SCOPE_AGENT);
    int g_ = 0;
    while (__hip_atomic_load(preb, __ATOMIC_RELAXED, __HIP_MEMORY_SCOPE_AGENT) < 256u) {
      __builtin_amdgcn_s_sleep(2);
      if (++g_ > (1 << 17)) break;
    }
    unsigned int exp0 = 0;
    isLeader = __hip_atomic_compare_exchange_strong(ep, &exp0, 1u,
                 __ATOMIC_RELAXED, __ATOMIC_RELAXED, __HIP_MEMORY_SCOPE_AGENT);
    nblkx = __hip_atomic_load(xcnt, __ATOMIC_RELAXED, __HIP_MEMORY_SCOPE_AGENT);
    asm volatile("s_waitcnt vmcnt(0)" ::: "memory");
  }
  __syncthreads();

  float c0 = 0.f, c1 = 0.f;

  #pragma unroll 1
  for (int tau = 0; tau <= TT; ++tau) {
    const _Float16* h0prev = h0buf + ((tau + 1) & 1) * (BB * HH);
    _Float16*       h0w    = h0buf + ((tau    ) & 1) * (BB * HH);
    const _Float16* h1prev = h1buf + ((tau    ) & 1) * (BB * HH);
    _Float16*       h1w    = h1buf + ((tau + 1) & 1) * (BB * HH);
    const _Float16* xt     = x16 + (size_t)tau * (BB * II);

    half8 P0[4], P1[4], P2[4], P3[4], P4[4];   // L0 staging (80 regs)
    half8 Q0[4], Q1[4], Q2[4], Q3[4];          // L1 staging, reused for both halves
    unsigned short hv0 = 0, hv1 = 0;           // deferred h values

    // ---------------- layer 0 (loads-only counted ladder) ----------------
    if (tau < TT) {
      ALOADG(P0, L0BASE(0)); ALOADG(P1, L0BASE(1)); ALOADG(P2, L0BASE(2));
      ALOADG(P3, L0BASE(3)); ALOADG(P4, L0BASE(4));
      f32x4 acc0[2][4];
      #pragma unroll
      for (int t = 0; t < 2; ++t)
        #pragma unroll
        for (int f = 0; f < 4; ++f) acc0[t][f] = (f32x4){0.f, 0.f, 0.f, 0.f};
      VW(16); MFMA8(acc0, P0, A0, 0);
      VW(12); MFMA8(acc0, P1, A0, 1);
      VW(8);  MFMA8(acc0, P2, A0, 2);
      VW(4);  MFMA8(acc0, P3, A0, 3);
      VW(0);  MFMA8(acc0, P4, A0, 4);
      SB;
      if (tau >= 1) {
        ALOADG(Q0, L1BASE(0)); ALOADG(Q1, L1BASE(1));
        ALOADG(Q2, L1BASE(2)); ALOADG(Q3, L1BASE(3));
      }
      SB;
      #pragma unroll
      for (int t = 0; t < 2; ++t)
        #pragma unroll
        for (int f = 0; f < 4; ++f)
          *(f32x4*)&red[wid * 2048 + (t * 4 + f) * 256 + lane * 4] = acc0[t][f];
      __syncthreads();
      f32x4 r = {0.f, 0.f, 0.f, 0.f};
      #pragma unroll
      for (int s = 0; s < 8; ++s)
        r += *(const f32x4*)&red[s * 2048 + wid * 256 + lane * 4];
      r += bs0;
      const float gi = sigmoidf_(r[0]);
      const float gf = sigmoidf_(r[1]);
      const float gg = tanhf_(r[2]);
      const float go_ = sigmoidf_(r[3]);
      c0 = gf * c0 + gi * gg;
      _Float16 h_ = (_Float16)(go_ * tanhf_(c0));
      hv0 = __builtin_bit_cast(unsigned short, h_);   // store deferred to end of step
    } else {
      ALOADG(Q0, L1BASE(0)); ALOADG(Q1, L1BASE(1));
      ALOADG(Q2, L1BASE(2)); ALOADG(Q3, L1BASE(3));
    }

    if (tau >= 1 && tau < TT) __syncthreads();   // WAR guard on red between layer reduces

    // ---------------- layer 1 (step tau-1): loads-only ladder, Q reuse ----------------
    if (tau >= 1) {
      f32x4 acc1[2][4];
      #pragma unroll
      for (int t = 0; t < 2; ++t)
        #pragma unroll
        for (int f = 0; f < 4; ++f) acc1[t][f] = (f32x4){0.f, 0.f, 0.f, 0.f};
      VW(12); MFMA8(acc1, Q0, A1, 0); ALOADG(Q0, L1BASE(4));
      VW(12); MFMA8(acc1, Q1, A1, 1); ALOADG(Q1, L1BASE(5));
      VW(12); MFMA8(acc1, Q2, A1, 2); ALOADG(Q2, L1BASE(6));
      VW(12); MFMA8(acc1, Q3, A1, 3); ALOADG(Q3, L1BASE(7));
      VW(12); MFMA8(acc1, Q0, A1, 4);
      VW(8);  MFMA8(acc1, Q1, A1, 5);
      VW(4);  MFMA8(acc1, Q2, A1, 6);
      VW(0);  MFMA8(acc1, Q3, A1, 7);
      SB;
      #pragma unroll
      for (int t = 0; t < 2; ++t)
        #pragma unroll
        for (int f = 0; f < 4; ++f)
          *(f32x4*)&red[wid * 2048 + (t * 4 + f) * 256 + lane * 4] = acc1[t][f];
      __syncthreads();
      f32x4 r = {0.f, 0.f, 0.f, 0.f};
      #pragma unroll
      for (int s = 0; s < 8; ++s)
        r += *(const f32x4*)&red[s * 2048 + wid * 256 + lane * 4];
      r += bs1;
      const float gi = sigmoidf_(r[0]);
      const float gf = sigmoidf_(r[1]);
      const float gg = tanhf_(r[2]);
      const float go_ = sigmoidf_(r[3]);
      c1 = gf * c1 + gi * gg;
      _Float16 h_ = (_Float16)(go_ * tanhf_(c1));
      hv1 = __builtin_bit_cast(unsigned short, h_);
    }

    // ---- deferred h-stores: AFTER all loads of this step have been issued ----
    if (tau < TT) HSTORE(h0w + hwIdx, (unsigned int)hv0);
    if (tau >= 1) HSTORE(h1w + hwIdx, (unsigned int)hv1);

    // ---- barrier v3: per-XCD leader does the single wbl2 + inv ----
    if (tau < TT) {
      asm volatile("s_waitcnt vmcnt(0)" ::: "memory");   // all waves: h-stores now in L2
      __syncthreads();
      if (tid == 0) {
        __hip_atomic_fetch_add(xarr, 1u, __ATOMIC_RELAXED, __HIP_MEMORY_SCOPE_AGENT);
        const unsigned int step1 = (unsigned int)(tau + 1);
        if (isLeader) {
          const unsigned int atgt = nblkx * step1;
          int g_ = 0;
          while (__hip_atomic_load(xarr, __ATOMIC_RELAXED, __HIP_MEMORY_SCOPE_AGENT) < atgt) {
            __builtin_amdgcn_s_sleep(1);
            if (++g_ > (1 << 17)) break;
          }
          __builtin_amdgcn_fence(__ATOMIC_RELEASE, "agent");   // ONE wbl2 per XCD
          __hip_atomic_fetch_add(rootc, nblkx, __ATOMIC_RELAXED, __HIP_MEMORY_SCOPE_AGENT);
          const unsigned int rtgt = 256u * step1;
          g_ = 0;
          while (__hip_atomic_load(rootc, __ATOMIC_RELAXED, __HIP_MEMORY_SCOPE_AGENT) < rtgt) {
            __builtin_amdgcn_s_sleep(1);
            if (++g_ > (1 << 17)) break;
          }
          __builtin_amdgcn_fence(__ATOMIC_ACQUIRE, "agent");   // ONE inv per XCD
          __hip_atomic_store(go, step1, __ATOMIC_RELAXED, __HIP_MEMORY_SCOPE_AGENT);
        } else {
          int g_ = 0;
          while (__hip_atomic_load(go, __ATOMIC_RELAXED, __HIP_MEMORY_SCOPE_AGENT) < step1) {
            __builtin_amdgcn_s_sleep(2);
            if (++g_ > (1 << 17)) break;
          }
        }
        asm volatile("s_waitcnt vmcnt(0)" ::: "memory");   // drain polls / go-store
      }
      __syncthreads();
    }
  }

  // final drain: untracked h1 store must complete before kernel end (fc reads it next)
  asm volatile("s_waitcnt vmcnt(0)" ::: "memory");
}

// ---- final projection on frag-major perm'd h + perm'd Wfc ----
__global__ __launch_bounds__(128) void fc_kernel(const _Float16* __restrict__ h,
    const float* __restrict__ wfcp, const float* __restrict__ bfc, float* __restrict__ out) {
  const int b = blockIdx.x;
  const int o = threadIdx.x;
  const float* wr = wfcp + (size_t)o * HH;
  float s = 0.f;
  #pragma unroll 2
  for (int g = 0; g < 32; ++g) {
    const _Float16* hr = h + ((size_t)g * BB + b) * 32;
    const float* w = wr + g * 32;
    #pragma unroll
    for (int k = 0; k < 32; k += 4) {
      float4 wv = *(const float4*)(w + k);
      half4v hv = *(const half4v*)(hr + k);
      s += (float)hv[0]*wv.x + (float)hv[1]*wv.y + (float)hv[2]*wv.z + (float)hv[3]*wv.w;
    }
  }
  out[(size_t)b * 128 + o] = s + bfc[o];
}

extern "C" void kernel_launch(void* const* d_in, const int* in_sizes, int n_in,
                              void* d_out, int out_size, void* d_ws, size_t ws_size,
                              hipStream_t stream) {
  const float* x    = (const float*)d_in[0];
  const float* Wih0 = (const float*)d_in[1];
  const float* Whh0 = (const float*)d_in[2];
  const float* bih0 = (const float*)d_in[3];
  const float* bhh0 = (const float*)d_in[4];
  const float* Wih1 = (const float*)d_in[5];
  const float* Whh1 = (const float*)d_in[6];
  const float* bih1 = (const float*)d_in[7];
  const float* bhh1 = (const float*)d_in[8];
  const float* Wfc  = (const float*)d_in[9];
  const float* bfc  = (const float*)d_in[10];
  float* out = (float*)d_out;

  char* ws = (char*)d_ws;
  size_t off = 0;
  auto alloc = [&](size_t bytes) -> void* {
    void* p = ws + off;
    off += (bytes + 255) & ~(size_t)255;
    return p;
  };
  _Float16* x16 = (_Float16*)alloc((size_t)BB * TT * II * 2);
  _Float16* w0r = (_Float16*)alloc((size_t)4096 * K0 * 2);
  _Float16* w1r = (_Float16*)alloc((size_t)4096 * K1 * 2);
  float* bias0  = (float*)alloc(4096 * 4);
  float* bias1  = (float*)alloc(4096 * 4);
  float* wfcp   = (float*)alloc((size_t)128 * HH * 4);
  const size_t cntBytes = 64 * 64 * 4;                 // lines 0..33 used, 256B stride
  const size_t stateBytes = cntBytes + (size_t)2 * BB * HH * 2 * 2;
  char* states  = (char*)alloc(stateBytes);
  unsigned int* cnt = (unsigned int*)states;
  _Float16* h0buf = (_Float16*)(states + cntBytes);
  _Float16* h1buf = h0buf + 2 * BB * HH;

  hipMemsetAsync(states, 0, stateBytes, stream);

  cvt_x_kernel<<<dim3(BB * TT * II / 8 / 256), 256, 0, stream>>>(x, x16);
  prep_w_kernel<<<dim3(K0 / 256, 4096), 256, 0, stream>>>(Wih0, Whh0, bih0, bhh0, w0r, bias0, II);
  prep_w_kernel<<<dim3(K1 / 256, 4096), 256, 0, stream>>>(Wih1, Whh1, bih1, bhh1, w1r, bias1, HH);
  prep_wfc_kernel<<<dim3(128 * HH / 256), 256, 0, stream>>>(Wfc, wfcp);

  void* args[] = { (void*)&w0r, (void*)&w1r, (void*)&bias0, (void*)&bias1,
                   (void*)&x16, (void*)&h0buf, (void*)&h1buf, (void*)&cnt };
  hipLaunchCooperativeKernel((void*)lstm_persist, dim3(256), dim3(512), args, 0, stream);

  fc_kernel<<<dim3(BB), 128, 0, stream>>>(h1buf + (size_t)BB * HH, wfcp, bfc, out);
}

// Round 13
// 6376.004 us; speedup vs baseline: 2.6192x; 1.0042x over previous
//
#include <hip/hip_runtime.h>
#include <cmath>

#define BB 128
#define TT 512
#define II 256
#define HH 1024
#define K0 1280            // layer0 K (256 x + 1024 h)
#define K1 2048            // layer1 K (1024 feed + 1024 rec)
#define FRAG (BB * 32)     // elems per k-frag panel [128 batch][32 k]

typedef _Float16 half4v __attribute__((ext_vector_type(4)));
typedef _Float16 half8  __attribute__((ext_vector_type(8)));
typedef float    f32x4  __attribute__((ext_vector_type(4)));

__device__ __forceinline__ float sigmoidf_(float x) { return 1.0f / (1.0f + __expf(-x)); }
__device__ __forceinline__ float tanhf_(float x) {
  float xc = fminf(fmaxf(x, -15.f), 15.f);
  float e = __expf(2.f * xc);
  return (e - 1.f) / (e + 1.f);
}

// K-perm within each 32-block: storage p -> logical o
__device__ __host__ __forceinline__ int invP(int p) {
  return 16 * ((p >> 2) & 1) + 4 * (p >> 3) + (p & 3);
}
__device__ __forceinline__ int permP(int o) {
  return 8 * ((o & 15) >> 2) + 4 * (o >> 4) + (o & 3);
}

// ---- convert x fp32 [B][T][I] -> fp16 frag-major [T][g=I/32][B][32perm] ----
__global__ __launch_bounds__(256) void cvt_x_kernel(const float* __restrict__ x,
                                                    _Float16* __restrict__ x16) {
  const int n = blockIdx.x * blockDim.x + threadIdx.x;
  const int q   = n & 3;
  const int b   = (n >> 2) & (BB - 1);
  const int tg  = n >> 9;
  const int t = tg >> 3;
  const int g = tg & 7;
  const float* src = x + ((size_t)b * TT + t) * II + 32 * g;
  const float4 lo = *(const float4*)(src + 4 * q);
  const float4 hi = *(const float4*)(src + 16 + 4 * q);
  half8 o = { (_Float16)lo.x, (_Float16)lo.y, (_Float16)lo.z, (_Float16)lo.w,
              (_Float16)hi.x, (_Float16)hi.y, (_Float16)hi.z, (_Float16)hi.w };
  *(half8*)(x16 + ((size_t)tg * BB + b) * 32 + 8 * q) = o;
}

// ---- gate-interleaved + K-permuted fp16 weight [4096][Ktot]; row' = 4*j + gate ----
__global__ __launch_bounds__(256) void prep_w_kernel(const float* __restrict__ Wih,
    const float* __restrict__ Whh, const float* __restrict__ bih, const float* __restrict__ bhh,
    _Float16* __restrict__ Wr, float* __restrict__ biasr, int Kin) {
  const int Ktot = Kin + HH;
  const int row  = blockIdx.y;
  const int k    = blockIdx.x * blockDim.x + threadIdx.x;
  const int jj = row >> 2, gate = row & 3;
  const int orow = gate * HH + jj;
  if (k < Ktot) {
    const int klog = 32 * (k >> 5) + invP(k & 31);
    float v = (klog < Kin) ? Wih[(size_t)orow * Kin + klog] : Whh[(size_t)orow * HH + (klog - Kin)];
    Wr[(size_t)row * Ktot + k] = (_Float16)v;
  }
  if (blockIdx.x == 0 && threadIdx.x == 0) biasr[row] = bih[orow] + bhh[orow];
}

// ---- K-permuted copy of Wfc ----
__global__ __launch_bounds__(256) void prep_wfc_kernel(const float* __restrict__ Wfc,
                                                       float* __restrict__ wfcp) {
  const int n = blockIdx.x * blockDim.x + threadIdx.x;
  const int k = n & (HH - 1);
  const int o = n >> 10;
  wfcp[n] = Wfc[(size_t)o * HH + 32 * (k >> 5) + invP(k & 31)];
}

#define SB __builtin_amdgcn_sched_barrier(0)
#define VW(n) { asm volatile("s_waitcnt vmcnt(" #n ")" ::: "memory"); SB; }

// sc0 = L1-bypass, L2-served. Untracked by compiler -> stays in flight across barriers.
#define ALOADG(U, BASE) { \
  const _Float16* p_ = (const _Float16*)(BASE) + boff; \
  asm volatile("global_load_dwordx4 %0, %1, off sc0"             : "=v"(U[0]) : "v"(p_)); \
  asm volatile("global_load_dwordx4 %0, %1, off offset:1024 sc0" : "=v"(U[1]) : "v"(p_)); \
  asm volatile("global_load_dwordx4 %0, %1, off offset:2048 sc0" : "=v"(U[2]) : "v"(p_)); \
  asm volatile("global_load_dwordx4 %0, %1, off offset:3072 sc0" : "=v"(U[3]) : "v"(p_)); }

// 2B h-store, WRITE-THROUGH to L3 (sc0 sc1): no dirty L2 line -> no wbl2 needed.
// vmcnt retires on L3 ack, so all-wave vmcnt(0) before arrival == publication.
#define HSTORE(PTR, VAL) { unsigned int d_ = (VAL); \
  asm volatile("global_store_short %0, %1, off sc0 sc1" :: "v"(PTR), "v"(d_) : "memory"); }

// 8 MFMAs: 2 row-tiles x 4 batch-frags, k-frag index kf (literal)
#define MFMA8(ACC, U, Aarr, kf) { \
  _Pragma("unroll") for (int f_ = 0; f_ < 4; ++f_) { \
    ACC[0][f_] = __builtin_amdgcn_mfma_f32_16x16x32_f16(Aarr[0][kf], U[f_], ACC[0][f_], 0, 0, 0); \
    ACC[1][f_] = __builtin_amdgcn_mfma_f32_16x16x32_f16(Aarr[1][kf], U[f_], ACC[1][f_], 0, 0, 0); } }

#define L0BASE(f) ((5 * wid + (f)) < 8 ? xt + (5 * wid + (f)) * FRAG \
                                       : h0prev + ((5 * wid + (f)) - 8) * FRAG)
#define L1BASE(f) ((wid < 4) ? h0prev + (8 * wid + (f)) * FRAG \
                             : h1prev + (8 * (wid - 4) + (f)) * FRAG)

// ---- persistent LSTM: loads-only ladders, write-through h, fused single-sync reduce,
//      barrier v4 (no wbl2; one inv per XCD per step) ----
__global__ __launch_bounds__(512, 1) void lstm_persist(
    const _Float16* __restrict__ w0r, const _Float16* __restrict__ w1r,
    const float* __restrict__ bias0, const float* __restrict__ bias1,
    const _Float16* __restrict__ x16,
    _Float16* __restrict__ h0buf, _Float16* __restrict__ h1buf,
    unsigned int* cnt)
{
  __shared__ float red[2][8 * 2048];   // 128KB of 160KB: separate L0/L1 reduce arenas
  const int tid  = threadIdx.x;
  const int lane = tid & 63;
  const int wid  = tid >> 6;
  const int l15  = lane & 15;
  const int kl   = lane >> 4;
  const int bid  = blockIdx.x;
  const int grp  = bid >> 7;
  const int lbid = bid & 127;

  // ---- A tiles -> registers: 2 row-tiles, K-slice per wave ----
  half8 A0[2][5], A1[2][8];
  #pragma unroll
  for (int t = 0; t < 2; ++t) {
    const _Float16* base0 = w0r + (size_t)(32 * lbid + 16 * t + l15) * K0 + 8 * kl;
    #pragma unroll
    for (int f = 0; f < 5; ++f) A0[t][f] = *(const half8*)(base0 + 32 * (5 * wid + f));
    const _Float16* base1 = w1r + (size_t)(32 * lbid + 16 * t + l15) * K1 + 8 * kl;
    #pragma unroll
    for (int f = 0; f < 8; ++f) A1[t][f] = *(const half8*)(base1 + 32 * (8 * wid + f));
  }
  const int t_own = wid >> 2, f_own = wid & 3;
  const f32x4 bs0 = *(const f32x4*)(bias0 + 32 * lbid + 16 * t_own + 4 * kl);
  const f32x4 bs1 = *(const f32x4*)(bias1 + 32 * lbid + 16 * t_own + 4 * kl);

  const int jj = 8 * lbid + 4 * t_own + kl;          // hidden unit this lane owns
  const int bb = 64 * grp + 16 * f_own + l15;        // batch element this lane owns
  const size_t hwIdx = ((size_t)(jj >> 5) * BB + bb) * 32 + permP(jj & 31);
  const int boff = grp * 2048 + l15 * 32 + 8 * kl;   // within-frag load offset (halfs)

  // cnt lines (256B stride): [0..7] xcd arrivals, [8..15] xcd go, [16] root,
  //                          [17..24] election, [25..32] xcd block count, [33] pre-barrier
  unsigned int xcd;
  asm volatile("s_getreg_b32 %0, hwreg(HW_REG_XCC_ID)" : "=s"(xcd));
  xcd &= 7u;
  unsigned int* xarr   = cnt + (0  + xcd) * 64;
  unsigned int* go     = cnt + (8  + xcd) * 64;
  unsigned int* rootc  = cnt + 16 * 64;
  unsigned int* ep     = cnt + (17 + xcd) * 64;
  unsigned int* xcnt   = cnt + (25 + xcd) * 64;
  unsigned int* preb   = cnt + 33 * 64;

  // ---- pre-loop: count blocks per XCD, flat pre-barrier, elect persistent leader ----
  bool isLeader = false;
  unsigned int nblkx = 0;
  if (tid == 0) {
    __hip_atomic_fetch_add(xcnt, 1u, __ATOMIC_RELAXED, __HIP_MEMORY_SCOPE_AGENT);
    asm volatile("s_waitcnt vmcnt(0)" ::: "memory");
    __hip_atomic_fetch_add(preb, 1u, __ATOMIC_RELAXED, __HIP_MEMORY_SCOPE_AGENT);
    int g_ = 0;
    while (__hip_atomic_load(preb, __ATOMIC_RELAXED, __HIP_MEMORY_SCOPE_AGENT) < 256u) {
      __builtin_amdgcn_s_sleep(2);
      if (++g_ > (1 << 17)) break;
    }
    unsigned int exp0 = 0;
    isLeader = __hip_atomic_compare_exchange_strong(ep, &exp0, 1u,
                 __ATOMIC_RELAXED, __ATOMIC_RELAXED, __HIP_MEMORY_SCOPE_AGENT);
    nblkx = __hip_atomic_load(xcnt, __ATOMIC_RELAXED, __HIP_MEMORY_SCOPE_AGENT);
    asm volatile("s_waitcnt vmcnt(0)" ::: "memory");
  }
  __syncthreads();

  float c0 = 0.f, c1 = 0.f;

  #pragma unroll 1
  for (int tau = 0; tau <= TT; ++tau) {
    const _Float16* h0prev = h0buf + ((tau + 1) & 1) * (BB * HH);
    _Float16*       h0w    = h0buf + ((tau    ) & 1) * (BB * HH);
    const _Float16* h1prev = h1buf + ((tau    ) & 1) * (BB * HH);
    _Float16*       h1w    = h1buf + ((tau + 1) & 1) * (BB * HH);
    const _Float16* xt     = x16 + (size_t)tau * (BB * II);

    half8 P0[4], P1[4], P2[4], P3[4], P4[4];   // L0 staging (80 regs)
    half8 Q0[4], Q1[4], Q2[4], Q3[4];          // L1 staging, reused for both halves

    // ---------------- layer 0: loads-only ladder; acc0 -> red[0] (no sync yet) ----------
    if (tau < TT) {
      ALOADG(P0, L0BASE(0)); ALOADG(P1, L0BASE(1)); ALOADG(P2, L0BASE(2));
      ALOADG(P3, L0BASE(3)); ALOADG(P4, L0BASE(4));
      f32x4 acc0[2][4];
      #pragma unroll
      for (int t = 0; t < 2; ++t)
        #pragma unroll
        for (int f = 0; f < 4; ++f) acc0[t][f] = (f32x4){0.f, 0.f, 0.f, 0.f};
      VW(16); MFMA8(acc0, P0, A0, 0);
      VW(12); MFMA8(acc0, P1, A0, 1);
      VW(8);  MFMA8(acc0, P2, A0, 2);
      VW(4);  MFMA8(acc0, P3, A0, 3);
      VW(0);  MFMA8(acc0, P4, A0, 4);
      SB;
      if (tau >= 1) {
        ALOADG(Q0, L1BASE(0)); ALOADG(Q1, L1BASE(1));
        ALOADG(Q2, L1BASE(2)); ALOADG(Q3, L1BASE(3));
      }
      SB;
      #pragma unroll
      for (int t = 0; t < 2; ++t)
        #pragma unroll
        for (int f = 0; f < 4; ++f)
          *(f32x4*)&red[0][wid * 2048 + (t * 4 + f) * 256 + lane * 4] = acc0[t][f];
    } else {
      ALOADG(Q0, L1BASE(0)); ALOADG(Q1, L1BASE(1));
      ALOADG(Q2, L1BASE(2)); ALOADG(Q3, L1BASE(3));
    }

    // ---------------- layer 1 (step tau-1): loads-only ladder; acc1 -> red[1] ----------
    if (tau >= 1) {
      f32x4 acc1[2][4];
      #pragma unroll
      for (int t = 0; t < 2; ++t)
        #pragma unroll
        for (int f = 0; f < 4; ++f) acc1[t][f] = (f32x4){0.f, 0.f, 0.f, 0.f};
      VW(12); MFMA8(acc1, Q0, A1, 0); ALOADG(Q0, L1BASE(4));
      VW(12); MFMA8(acc1, Q1, A1, 1); ALOADG(Q1, L1BASE(5));
      VW(12); MFMA8(acc1, Q2, A1, 2); ALOADG(Q2, L1BASE(6));
      VW(12); MFMA8(acc1, Q3, A1, 3); ALOADG(Q3, L1BASE(7));
      VW(12); MFMA8(acc1, Q0, A1, 4);
      VW(8);  MFMA8(acc1, Q1, A1, 5);
      VW(4);  MFMA8(acc1, Q2, A1, 6);
      VW(0);  MFMA8(acc1, Q3, A1, 7);
      SB;
      #pragma unroll
      for (int t = 0; t < 2; ++t)
        #pragma unroll
        for (int f = 0; f < 4; ++f)
          *(f32x4*)&red[1][wid * 2048 + (t * 4 + f) * 256 + lane * 4] = acc1[t][f];
    }

    // ---------------- ONE sync, then both epilogues + write-through stores -------------
    __syncthreads();
    if (tau < TT) {
      f32x4 r = {0.f, 0.f, 0.f, 0.f};
      #pragma unroll
      for (int s = 0; s < 8; ++s)
        r += *(const f32x4*)&red[0][s * 2048 + wid * 256 + lane * 4];
      r += bs0;
      const float gi = sigmoidf_(r[0]);
      const float gf = sigmoidf_(r[1]);
      const float gg = tanhf_(r[2]);
      const float go_ = sigmoidf_(r[3]);
      c0 = gf * c0 + gi * gg;
      _Float16 h_ = (_Float16)(go_ * tanhf_(c0));
      HSTORE(h0w + hwIdx, (unsigned int)__builtin_bit_cast(unsigned short, h_));
    }
    if (tau >= 1) {
      f32x4 r = {0.f, 0.f, 0.f, 0.f};
      #pragma unroll
      for (int s = 0; s < 8; ++s)
        r += *(const f32x4*)&red[1][s * 2048 + wid * 256 + lane * 4];
      r += bs1;
      const float gi = sigmoidf_(r[0]);
      const float gf = sigmoidf_(r[1]);
      const float gg = tanhf_(r[2]);
      const float go_ = sigmoidf_(r[3]);
      c1 = gf * c1 + gi * gg;
      _Float16 h_ = (_Float16)(go_ * tanhf_(c1));
      HSTORE(h1w + hwIdx, (unsigned int)__builtin_bit_cast(unsigned short, h_));
    }

    // ---- barrier v4: all-wave L3-ack drain -> arrivals -> root -> ONE inv -> go ----
    if (tau < TT) {
      asm volatile("s_waitcnt vmcnt(0)" ::: "memory");   // write-through stores ack'd by L3
      __syncthreads();
      if (tid == 0) {
        __hip_atomic_fetch_add(xarr, 1u, __ATOMIC_RELAXED, __HIP_MEMORY_SCOPE_AGENT);
        const unsigned int step1 = (unsigned int)(tau + 1);
        if (isLeader) {
          const unsigned int atgt = nblkx * step1;
          int g_ = 0;
          while (__hip_atomic_load(xarr, __ATOMIC_RELAXED, __HIP_MEMORY_SCOPE_AGENT) < atgt) {
            __builtin_amdgcn_s_sleep(1);
            if (++g_ > (1 << 17)) break;
          }
          __hip_atomic_fetch_add(rootc, nblkx, __ATOMIC_RELAXED, __HIP_MEMORY_SCOPE_AGENT);
          const unsigned int rtgt = 256u * step1;
          g_ = 0;
          while (__hip_atomic_load(rootc, __ATOMIC_RELAXED, __HIP_MEMORY_SCOPE_AGENT) < rtgt) {
            __builtin_amdgcn_s_sleep(1);
            if (++g_ > (1 << 17)) break;
          }
          __builtin_amdgcn_fence(__ATOMIC_ACQUIRE, "agent");   // ONE inv per XCD
          __hip_atomic_store(go, step1, __ATOMIC_RELAXED, __HIP_MEMORY_SCOPE_AGENT);
        } else {
          int g_ = 0;
          while (__hip_atomic_load(go, __ATOMIC_RELAXED, __HIP_MEMORY_SCOPE_AGENT) < step1) {
            __builtin_amdgcn_s_sleep(2);
            if (++g_ > (1 << 17)) break;
          }
        }
        asm volatile("s_waitcnt vmcnt(0)" ::: "memory");   // drain polls / go-store
      }
      __syncthreads();
    }
  }

  // final drain: untracked h1 store must complete before kernel end (fc reads it next)
  asm volatile("s_waitcnt vmcnt(0)" ::: "memory");
}

// ---- final projection on frag-major perm'd h + perm'd Wfc ----
__global__ __launch_bounds__(128) void fc_kernel(const _Float16* __restrict__ h,
    const float* __restrict__ wfcp, const float* __restrict__ bfc, float* __restrict__ out) {
  const int b = blockIdx.x;
  const int o = threadIdx.x;
  const float* wr = wfcp + (size_t)o * HH;
  float s = 0.f;
  #pragma unroll 2
  for (int g = 0; g < 32; ++g) {
    const _Float16* hr = h + ((size_t)g * BB + b) * 32;
    const float* w = wr + g * 32;
    #pragma unroll
    for (int k = 0; k < 32; k += 4) {
      float4 wv = *(const float4*)(w + k);
      half4v hv = *(const half4v*)(hr + k);
      s += (float)hv[0]*wv.x + (float)hv[1]*wv.y + (float)hv[2]*wv.z + (float)hv[3]*wv.w;
    }
  }
  out[(size_t)b * 128 + o] = s + bfc[o];
}

extern "C" void kernel_launch(void* const* d_in, const int* in_sizes, int n_in,
                              void* d_out, int out_size, void* d_ws, size_t ws_size,
                              hipStream_t stream) {
  const float* x    = (const float*)d_in[0];
  const float* Wih0 = (const float*)d_in[1];
  const float* Whh0 = (const float*)d_in[2];
  const float* bih0 = (const float*)d_in[3];
  const float* bhh0 = (const float*)d_in[4];
  const float* Wih1 = (const float*)d_in[5];
  const float* Whh1 = (const float*)d_in[6];
  const float* bih1 = (const float*)d_in[7];
  const float* bhh1 = (const float*)d_in[8];
  const float* Wfc  = (const float*)d_in[9];
  const float* bfc  = (const float*)d_in[10];
  float* out = (float*)d_out;

  char* ws = (char*)d_ws;
  size_t off = 0;
  auto alloc = [&](size_t bytes) -> void* {
    void* p = ws + off;
    off += (bytes + 255) & ~(size_t)255;
    return p;
  };
  _Float16* x16 = (_Float16*)alloc((size_t)BB * TT * II * 2);
  _Float16* w0r = (_Float16*)alloc((size_t)4096 * K0 * 2);
  _Float16* w1r = (_Float16*)alloc((size_t)4096 * K1 * 2);
  float* bias0  = (float*)alloc(4096 * 4);
  float* bias1  = (float*)alloc(4096 * 4);
  float* wfcp   = (float*)alloc((size_t)128 * HH * 4);
  const size_t cntBytes = 64 * 64 * 4;                 // lines 0..33 used, 256B stride
  const size_t stateBytes = cntBytes + (size_t)2 * BB * HH * 2 * 2;
  char* states  = (char*)alloc(stateBytes);
  unsigned int* cnt = (unsigned int*)states;
  _Float16* h0buf = (_Float16*)(states + cntBytes);
  _Float16* h1buf = h0buf + 2 * BB * HH;

  hipMemsetAsync(states, 0, stateBytes, stream);

  cvt_x_kernel<<<dim3(BB * TT * II / 8 / 256), 256, 0, stream>>>(x, x16);
  prep_w_kernel<<<dim3(K0 / 256, 4096), 256, 0, stream>>>(Wih0, Whh0, bih0, bhh0, w0r, bias0, II);
  prep_w_kernel<<<dim3(K1 / 256, 4096), 256, 0, stream>>>(Wih1, Whh1, bih1, bhh1, w1r, bias1, HH);
  prep_wfc_kernel<<<dim3(128 * HH / 256), 256, 0, stream>>>(Wfc, wfcp);

  void* args[] = { (void*)&w0r, (void*)&w1r, (void*)&bias0, (void*)&bias1,
                   (void*)&x16, (void*)&h0buf, (void*)&h1buf, (void*)&cnt };
  hipLaunchCooperativeKernel((void*)lstm_persist, dim3(256), dim3(512), args, 0, stream);

  fc_kernel<<<dim3(BB), 128, 0, stream>>>(h1buf + (size_t)BB * HH, wfcp, bfc, out);
}

// Round 15
// 6051.476 us; speedup vs baseline: 2.7596x; 1.0536x over previous
//
#include <hip/hip_runtime.h>
#include <cmath>

#define BB 128
#define TT 512
#define II 256
#define HH 1024
#define K0 1280            // layer0 K (256 x + 1024 h)
#define K1 2048            // layer1 K (1024 feed + 1024 rec)
#define FRAG (BB * 32)     // elems per k-frag panel [128 batch][32 k]

typedef _Float16 half4v __attribute__((ext_vector_type(4)));
typedef _Float16 half8  __attribute__((ext_vector_type(8)));
typedef float    f32x4  __attribute__((ext_vector_type(4)));

__device__ __forceinline__ float sigmoidf_(float x) { return 1.0f / (1.0f + __expf(-x)); }
__device__ __forceinline__ float tanhf_(float x) {
  float xc = fminf(fmaxf(x, -15.f), 15.f);
  float e = __expf(2.f * xc);
  return (e - 1.f) / (e + 1.f);
}

// K-perm within each 32-block: storage p -> logical o
__device__ __host__ __forceinline__ int invP(int p) {
  return 16 * ((p >> 2) & 1) + 4 * (p >> 3) + (p & 3);
}
__device__ __forceinline__ int permP(int o) {
  return 8 * ((o & 15) >> 2) + 4 * (o >> 4) + (o & 3);
}

// ---- convert x fp32 [B][T][I] -> fp16 frag-major [T][g=I/32][B][32perm] ----
__global__ __launch_bounds__(256) void cvt_x_kernel(const float* __restrict__ x,
                                                    _Float16* __restrict__ x16) {
  const int n = blockIdx.x * blockDim.x + threadIdx.x;
  const int q   = n & 3;
  const int b   = (n >> 2) & (BB - 1);
  const int tg  = n >> 9;
  const int t = tg >> 3;
  const int g = tg & 7;
  const float* src = x + ((size_t)b * TT + t) * II + 32 * g;
  const float4 lo = *(const float4*)(src + 4 * q);
  const float4 hi = *(const float4*)(src + 16 + 4 * q);
  half8 o = { (_Float16)lo.x, (_Float16)lo.y, (_Float16)lo.z, (_Float16)lo.w,
              (_Float16)hi.x, (_Float16)hi.y, (_Float16)hi.z, (_Float16)hi.w };
  *(half8*)(x16 + ((size_t)tg * BB + b) * 32 + 8 * q) = o;
}

// ---- gate-interleaved + K-permuted fp16 weight [4096][Ktot]; row' = 4*j + gate ----
__global__ __launch_bounds__(256) void prep_w_kernel(const float* __restrict__ Wih,
    const float* __restrict__ Whh, const float* __restrict__ bih, const float* __restrict__ bhh,
    _Float16* __restrict__ Wr, float* __restrict__ biasr, int Kin) {
  const int Ktot = Kin + HH;
  const int row  = blockIdx.y;
  const int k    = blockIdx.x * blockDim.x + threadIdx.x;
  const int jj = row >> 2, gate = row & 3;
  const int orow = gate * HH + jj;
  if (k < Ktot) {
    const int klog = 32 * (k >> 5) + invP(k & 31);
    float v = (klog < Kin) ? Wih[(size_t)orow * Kin + klog] : Whh[(size_t)orow * HH + (klog - Kin)];
    Wr[(size_t)row * Ktot + k] = (_Float16)v;
  }
  if (blockIdx.x == 0 && threadIdx.x == 0) biasr[row] = bih[orow] + bhh[orow];
}

// ---- K-permuted copy of Wfc ----
__global__ __launch_bounds__(256) void prep_wfc_kernel(const float* __restrict__ Wfc,
                                                       float* __restrict__ wfcp) {
  const int n = blockIdx.x * blockDim.x + threadIdx.x;
  const int k = n & (HH - 1);
  const int o = n >> 10;
  wfcp[n] = Wfc[(size_t)o * HH + 32 * (k >> 5) + invP(k & 31)];
}

#define SB __builtin_amdgcn_sched_barrier(0)
#define VW(n) { asm volatile("s_waitcnt vmcnt(" #n ")" ::: "memory"); SB; }

// sc0 = L1-bypass, L2-served. Untracked by compiler -> stays in flight across barriers.
// NOTE: staging buffers for these must NEVER exceed the register budget — a spill of an
// in-flight asm-load destination saves pre-arrival garbage (r14 NaN lesson).
#define ALOADG(U, BASE) { \
  const _Float16* p_ = (const _Float16*)(BASE) + boff; \
  asm volatile("global_load_dwordx4 %0, %1, off sc0"             : "=v"(U[0]) : "v"(p_)); \
  asm volatile("global_load_dwordx4 %0, %1, off offset:1024 sc0" : "=v"(U[1]) : "v"(p_)); \
  asm volatile("global_load_dwordx4 %0, %1, off offset:2048 sc0" : "=v"(U[2]) : "v"(p_)); \
  asm volatile("global_load_dwordx4 %0, %1, off offset:3072 sc0" : "=v"(U[3]) : "v"(p_)); }

// 2B h-store, WRITE-THROUGH to L3 (sc0 sc1): no dirty L2 line -> no wbl2 needed.
#define HSTORE(PTR, VAL) { unsigned int d_ = (VAL); \
  asm volatile("global_store_short %0, %1, off sc0 sc1" :: "v"(PTR), "v"(d_) : "memory"); }

// 8 MFMAs: 2 row-tiles x 4 batch-frags, k-frag index kf (literal)
#define MFMA8(ACC, U, Aarr, kf) { \
  _Pragma("unroll") for (int f_ = 0; f_ < 4; ++f_) { \
    ACC[0][f_] = __builtin_amdgcn_mfma_f32_16x16x32_f16(Aarr[0][kf], U[f_], ACC[0][f_], 0, 0, 0); \
    ACC[1][f_] = __builtin_amdgcn_mfma_f32_16x16x32_f16(Aarr[1][kf], U[f_], ACC[1][f_], 0, 0, 0); } }

#define L0BASE(f) ((5 * wid + (f)) < 8 ? xt + (5 * wid + (f)) * FRAG \
                                       : h0prev + ((5 * wid + (f)) - 8) * FRAG)
#define L1BASE(f) ((wid < 4) ? h0prev + (8 * wid + (f)) * FRAG \
                             : h1prev + (8 * (wid - 4) + (f)) * FRAG)

// ---- persistent LSTM: r13 load structure + barrier v5 (per-group, early inv) ----
__global__ __launch_bounds__(512, 1) void lstm_persist(
    const _Float16* __restrict__ w0r, const _Float16* __restrict__ w1r,
    const float* __restrict__ bias0, const float* __restrict__ bias1,
    const _Float16* __restrict__ x16,
    _Float16* __restrict__ h0buf, _Float16* __restrict__ h1buf,
    unsigned int* cnt)
{
  __shared__ float red[2][8 * 2048];   // 128KB of 160KB: separate L0/L1 reduce arenas
  const int tid  = threadIdx.x;
  const int lane = tid & 63;
  const int wid  = tid >> 6;
  const int l15  = lane & 15;
  const int kl   = lane >> 4;
  const int bid  = blockIdx.x;
  const int grp  = bid >> 7;
  const int lbid = bid & 127;

  // ---- A tiles -> registers: 2 row-tiles, K-slice per wave ----
  half8 A0[2][5], A1[2][8];
  #pragma unroll
  for (int t = 0; t < 2; ++t) {
    const _Float16* base0 = w0r + (size_t)(32 * lbid + 16 * t + l15) * K0 + 8 * kl;
    #pragma unroll
    for (int f = 0; f < 5; ++f) A0[t][f] = *(const half8*)(base0 + 32 * (5 * wid + f));
    const _Float16* base1 = w1r + (size_t)(32 * lbid + 16 * t + l15) * K1 + 8 * kl;
    #pragma unroll
    for (int f = 0; f < 8; ++f) A1[t][f] = *(const half8*)(base1 + 32 * (8 * wid + f));
  }
  const int t_own = wid >> 2, f_own = wid & 3;
  const f32x4 bs0 = *(const f32x4*)(bias0 + 32 * lbid + 16 * t_own + 4 * kl);
  const f32x4 bs1 = *(const f32x4*)(bias1 + 32 * lbid + 16 * t_own + 4 * kl);

  const int jj = 8 * lbid + 4 * t_own + kl;          // hidden unit this lane owns
  const int bb = 64 * grp + 16 * f_own + l15;        // batch element this lane owns
  const size_t hwIdx = ((size_t)(jj >> 5) * BB + bb) * 32 + permP(jj & 31);
  const int boff = grp * 2048 + l15 * 32 + 8 * kl;   // within-frag load offset (halfs)

  // cnt lines (256B stride): per (grp,xcd): xarr 0..15, go 16..31; root 32..33 (per grp);
  //                          ep 34..49, xcnt 50..65; preb 66
  unsigned int xcd;
  asm volatile("s_getreg_b32 %0, hwreg(HW_REG_XCC_ID)" : "=s"(xcd));
  xcd &= 7u;
  const int gx = grp * 8 + (int)xcd;
  unsigned int* xarr   = cnt + (0  + gx) * 64;
  unsigned int* go     = cnt + (16 + gx) * 64;
  unsigned int* rootc  = cnt + (32 + grp) * 64;
  unsigned int* ep     = cnt + (34 + gx) * 64;
  unsigned int* xcnt   = cnt + (50 + gx) * 64;
  unsigned int* preb   = cnt + 66 * 64;

  // ---- pre-loop: count blocks per (grp,xcd), flat pre-barrier, elect leader ----
  bool isLeader = false;
  unsigned int nblkx = 0;
  if (tid == 0) {
    __hip_atomic_fetch_add(xcnt, 1u, __ATOMIC_RELAXED, __HIP_MEMORY_SCOPE_AGENT);
    asm volatile("s_waitcnt vmcnt(0)" ::: "memory");
    __hip_atomic_fetch_add(preb, 1u, __ATOMIC_RELAXED, __HIP_MEMORY_SCOPE_AGENT);
    int g_ = 0;
    while (__hip_atomic_load(preb, __ATOMIC_RELAXED, __HIP_MEMORY_SCOPE_AGENT) < 256u) {
      __builtin_amdgcn_s_sleep(2);
      if (++g_ > (1 << 17)) break;
    }
    unsigned int exp0 = 0;
    isLeader = __hip_atomic_compare_exchange_strong(ep, &exp0, 1u,
                 __ATOMIC_RELAXED, __ATOMIC_RELAXED, __HIP_MEMORY_SCOPE_AGENT);
    nblkx = __hip_atomic_load(xcnt, __ATOMIC_RELAXED, __HIP_MEMORY_SCOPE_AGENT);
    asm volatile("s_waitcnt vmcnt(0)" ::: "memory");
  }
  __syncthreads();

  float c0 = 0.f, c1 = 0.f;

  #pragma unroll 1
  for (int tau = 0; tau <= TT; ++tau) {
    const _Float16* h0prev = h0buf + ((tau + 1) & 1) * (BB * HH);
    _Float16*       h0w    = h0buf + ((tau    ) & 1) * (BB * HH);
    const _Float16* h1prev = h1buf + ((tau    ) & 1) * (BB * HH);
    _Float16*       h1w    = h1buf + ((tau + 1) & 1) * (BB * HH);
    const _Float16* xt     = x16 + (size_t)tau * (BB * II);

    half8 P0[4], P1[4], P2[4], P3[4], P4[4];   // L0 staging (80 regs)
    half8 Q0[4], Q1[4], Q2[4], Q3[4];          // L1 staging, reused (issued after P dies)

    // ---------------- layer 0: loads-only ladder (r13 structure) ----------------
    if (tau < TT) {
      ALOADG(P0, L0BASE(0)); ALOADG(P1, L0BASE(1)); ALOADG(P2, L0BASE(2));
      ALOADG(P3, L0BASE(3)); ALOADG(P4, L0BASE(4));
      f32x4 acc0[2][4];
      #pragma unroll
      for (int t = 0; t < 2; ++t)
        #pragma unroll
        for (int f = 0; f < 4; ++f) acc0[t][f] = (f32x4){0.f, 0.f, 0.f, 0.f};
      VW(16); MFMA8(acc0, P0, A0, 0);
      VW(12); MFMA8(acc0, P1, A0, 1);
      VW(8);  MFMA8(acc0, P2, A0, 2);
      VW(4);  MFMA8(acc0, P3, A0, 3);
      VW(0);  MFMA8(acc0, P4, A0, 4);
      SB;
      if (tau >= 1) {
        ALOADG(Q0, L1BASE(0)); ALOADG(Q1, L1BASE(1));
        ALOADG(Q2, L1BASE(2)); ALOADG(Q3, L1BASE(3));
      }
      SB;
      #pragma unroll
      for (int t = 0; t < 2; ++t)
        #pragma unroll
        for (int f = 0; f < 4; ++f)
          *(f32x4*)&red[0][wid * 2048 + (t * 4 + f) * 256 + lane * 4] = acc0[t][f];
    } else {
      ALOADG(Q0, L1BASE(0)); ALOADG(Q1, L1BASE(1));
      ALOADG(Q2, L1BASE(2)); ALOADG(Q3, L1BASE(3));
    }

    // ---------------- layer 1 (step tau-1): loads-only ladder; acc1 -> red[1] ----------
    if (tau >= 1) {
      f32x4 acc1[2][4];
      #pragma unroll
      for (int t = 0; t < 2; ++t)
        #pragma unroll
        for (int f = 0; f < 4; ++f) acc1[t][f] = (f32x4){0.f, 0.f, 0.f, 0.f};
      VW(12); MFMA8(acc1, Q0, A1, 0); ALOADG(Q0, L1BASE(4));
      VW(12); MFMA8(acc1, Q1, A1, 1); ALOADG(Q1, L1BASE(5));
      VW(12); MFMA8(acc1, Q2, A1, 2); ALOADG(Q2, L1BASE(6));
      VW(12); MFMA8(acc1, Q3, A1, 3); ALOADG(Q3, L1BASE(7));
      VW(12); MFMA8(acc1, Q0, A1, 4);
      VW(8);  MFMA8(acc1, Q1, A1, 5);
      VW(4);  MFMA8(acc1, Q2, A1, 6);
      VW(0);  MFMA8(acc1, Q3, A1, 7);
      SB;
      #pragma unroll
      for (int t = 0; t < 2; ++t)
        #pragma unroll
        for (int f = 0; f < 4; ++f)
          *(f32x4*)&red[1][wid * 2048 + (t * 4 + f) * 256 + lane * 4] = acc1[t][f];
    }

    // ---------------- ONE sync, then both epilogues + write-through stores -------------
    __syncthreads();
    if (tau < TT) {
      f32x4 r = {0.f, 0.f, 0.f, 0.f};
      #pragma unroll
      for (int s = 0; s < 8; ++s)
        r += *(const f32x4*)&red[0][s * 2048 + wid * 256 + lane * 4];
      r += bs0;
      const float gi = sigmoidf_(r[0]);
      const float gf = sigmoidf_(r[1]);
      const float gg = tanhf_(r[2]);
      const float go_ = sigmoidf_(r[3]);
      c0 = gf * c0 + gi * gg;
      _Float16 h_ = (_Float16)(go_ * tanhf_(c0));
      HSTORE(h0w + hwIdx, (unsigned int)__builtin_bit_cast(unsigned short, h_));
    }
    if (tau >= 1) {
      f32x4 r = {0.f, 0.f, 0.f, 0.f};
      #pragma unroll
      for (int s = 0; s < 8; ++s)
        r += *(const f32x4*)&red[1][s * 2048 + wid * 256 + lane * 4];
      r += bs1;
      const float gi = sigmoidf_(r[0]);
      const float gf = sigmoidf_(r[1]);
      const float gg = tanhf_(r[2]);
      const float go_ = sigmoidf_(r[3]);
      c1 = gf * c1 + gi * gg;
      _Float16 h_ = (_Float16)(go_ * tanhf_(c1));
      HSTORE(h1w + hwIdx, (unsigned int)__builtin_bit_cast(unsigned short, h_));
    }

    // ---- barrier v5 (per group): drain -> arrive -> [leader: early inv, root, go] ----
    if (tau < TT) {
      asm volatile("s_waitcnt vmcnt(0)" ::: "memory");   // write-through stores ack'd by L3
      __syncthreads();
      if (tid == 0) {
        __hip_atomic_fetch_add(xarr, 1u, __ATOMIC_RELAXED, __HIP_MEMORY_SCOPE_AGENT);
        const unsigned int step1 = (unsigned int)(tau + 1);
        if (isLeader) {
          const unsigned int atgt = nblkx * step1;
          int g_ = 0;
          while (__hip_atomic_load(xarr, __ATOMIC_RELAXED, __HIP_MEMORY_SCOPE_AGENT) < atgt) {
            __builtin_amdgcn_s_sleep(1);
            if (++g_ > (1 << 17)) break;
          }
          // EARLY inv: this XCD's group blocks are parked; nothing re-caches their lines
          __builtin_amdgcn_fence(__ATOMIC_ACQUIRE, "agent");
          __hip_atomic_fetch_add(rootc, nblkx, __ATOMIC_RELAXED, __HIP_MEMORY_SCOPE_AGENT);
          const unsigned int rtgt = 128u * step1;      // per-group root: 128 blocks
          g_ = 0;
          while (__hip_atomic_load(rootc, __ATOMIC_RELAXED, __HIP_MEMORY_SCOPE_AGENT) < rtgt) {
            __builtin_amdgcn_s_sleep(1);
            if (++g_ > (1 << 17)) break;
          }
          __hip_atomic_store(go, step1, __ATOMIC_RELAXED, __HIP_MEMORY_SCOPE_AGENT);
        } else {
          int g_ = 0;
          while (__hip_atomic_load(go, __ATOMIC_RELAXED, __HIP_MEMORY_SCOPE_AGENT) < step1) {
            __builtin_amdgcn_s_sleep(1);
            if (++g_ > (1 << 17)) break;
          }
        }
        asm volatile("s_waitcnt vmcnt(0)" ::: "memory");   // drain polls / go-store
      }
      __syncthreads();
    }
  }

  // final drain: untracked h1 store must complete before kernel end (fc reads it next)
  asm volatile("s_waitcnt vmcnt(0)" ::: "memory");
}

// ---- final projection on frag-major perm'd h + perm'd Wfc ----
__global__ __launch_bounds__(128) void fc_kernel(const _Float16* __restrict__ h,
    const float* __restrict__ wfcp, const float* __restrict__ bfc, float* __restrict__ out) {
  const int b = blockIdx.x;
  const int o = threadIdx.x;
  const float* wr = wfcp + (size_t)o * HH;
  float s = 0.f;
  #pragma unroll 2
  for (int g = 0; g < 32; ++g) {
    const _Float16* hr = h + ((size_t)g * BB + b) * 32;
    const float* w = wr + g * 32;
    #pragma unroll
    for (int k = 0; k < 32; k += 4) {
      float4 wv = *(const float4*)(w + k);
      half4v hv = *(const half4v*)(hr + k);
      s += (float)hv[0]*wv.x + (float)hv[1]*wv.y + (float)hv[2]*wv.z + (float)hv[3]*wv.w;
    }
  }
  out[(size_t)b * 128 + o] = s + bfc[o];
}

extern "C" void kernel_launch(void* const* d_in, const int* in_sizes, int n_in,
                              void* d_out, int out_size, void* d_ws, size_t ws_size,
                              hipStream_t stream) {
  const float* x    = (const float*)d_in[0];
  const float* Wih0 = (const float*)d_in[1];
  const float* Whh0 = (const float*)d_in[2];
  const float* bih0 = (const float*)d_in[3];
  const float* bhh0 = (const float*)d_in[4];
  const float* Wih1 = (const float*)d_in[5];
  const float* Whh1 = (const float*)d_in[6];
  const float* bih1 = (const float*)d_in[7];
  const float* bhh1 = (const float*)d_in[8];
  const float* Wfc  = (const float*)d_in[9];
  const float* bfc  = (const float*)d_in[10];
  float* out = (float*)d_out;

  char* ws = (char*)d_ws;
  size_t off = 0;
  auto alloc = [&](size_t bytes) -> void* {
    void* p = ws + off;
    off += (bytes + 255) & ~(size_t)255;
    return p;
  };
  _Float16* x16 = (_Float16*)alloc((size_t)BB * TT * II * 2);
  _Float16* w0r = (_Float16*)alloc((size_t)4096 * K0 * 2);
  _Float16* w1r = (_Float16*)alloc((size_t)4096 * K1 * 2);
  float* bias0  = (float*)alloc(4096 * 4);
  float* bias1  = (float*)alloc(4096 * 4);
  float* wfcp   = (float*)alloc((size_t)128 * HH * 4);
  const size_t cntBytes = 128 * 64 * 4;                // lines 0..66 used, 256B stride
  const size_t stateBytes = cntBytes + (size_t)2 * BB * HH * 2 * 2;
  char* states  = (char*)alloc(stateBytes);
  unsigned int* cnt = (unsigned int*)states;
  _Float16* h0buf = (_Float16*)(states + cntBytes);
  _Float16* h1buf = h0buf + 2 * BB * HH;

  hipMemsetAsync(states, 0, stateBytes, stream);

  cvt_x_kernel<<<dim3(BB * TT * II / 8 / 256), 256, 0, stream>>>(x, x16);
  prep_w_kernel<<<dim3(K0 / 256, 4096), 256, 0, stream>>>(Wih0, Whh0, bih0, bhh0, w0r, bias0, II);
  prep_w_kernel<<<dim3(K1 / 256, 4096), 256, 0, stream>>>(Wih1, Whh1, bih1, bhh1, w1r, bias1, HH);
  prep_wfc_kernel<<<dim3(128 * HH / 256), 256, 0, stream>>>(Wfc, wfcp);

  void* args[] = { (void*)&w0r, (void*)&w1r, (void*)&bias0, (void*)&bias1,
                   (void*)&x16, (void*)&h0buf, (void*)&h1buf, (void*)&cnt };
  hipLaunchCooperativeKernel((void*)lstm_persist, dim3(256), dim3(512), args, 0, stream);

  fc_kernel<<<dim3(BB), 128, 0, stream>>>(h1buf + (size_t)BB * HH, wfcp, bfc, out);
}